// Round 1
// baseline (2072.202 us; speedup 1.0000x reference)
//
#include <hip/hip_runtime.h>

#define Bz 4
#define Tz 1024
#define Dz 1024
#define Hz 16
#define NTz (Bz*Tz)

typedef short s8v __attribute__((ext_vector_type(8)));
typedef float f4v __attribute__((ext_vector_type(4)));

__device__ __forceinline__ float bf2f(unsigned short u){
  unsigned int x = ((unsigned int)u) << 16;
  return __builtin_bit_cast(float, x);
}
__device__ __forceinline__ unsigned short f2bf(float f){
  unsigned int x = __builtin_bit_cast(unsigned int, f);
  x += 0x7fffu + ((x >> 16) & 1u);
  return (unsigned short)(x >> 16);
}
__device__ __forceinline__ float gelu_f(float x){
  float x3 = x*x*x;
  return 0.5f*x*(1.0f + tanhf(0.7978845608028654f*(x + 0.044715f*x3)));
}

// ---------------- convert + transpose: fp32 (R x C) -> bf16 (C x R) ----------
__global__ __launch_bounds__(256) void k_convtrans(const float* __restrict__ in,
    unsigned short* __restrict__ out, int R, int C, long sIn, long sOut)
{
  __shared__ float tile[32][33];
  in  += (long)blockIdx.z * sIn;
  out += (long)blockIdx.z * sOut;
  int c0 = blockIdx.x * 32, r0 = blockIdx.y * 32;
  int tx = threadIdx.x & 31, ty = threadIdx.x >> 5;
  #pragma unroll
  for (int i = 0; i < 32; i += 8)
    tile[ty + i][tx] = in[(long)(r0 + ty + i) * C + c0 + tx];
  __syncthreads();
  #pragma unroll
  for (int i = 0; i < 32; i += 8)
    out[(long)(c0 + ty + i) * R + r0 + tx] = f2bf(tile[tx][ty + i]);
}

// ---------------- layernorm: fp32 in -> bf16 out (row = 1024) ----------------
__global__ __launch_bounds__(256) void k_layernorm(const float* __restrict__ x,
    const float* __restrict__ w, const float* __restrict__ b,
    unsigned short* __restrict__ out)
{
  int row = blockIdx.x, tid = threadIdx.x;
  const float4* xp = (const float4*)(x + (long)row * Dz);
  float4 v = xp[tid];
  float s  = v.x + v.y + v.z + v.w;
  float ss = v.x*v.x + v.y*v.y + v.z*v.z + v.w*v.w;
  int lane = tid & 63, wv = tid >> 6;
  #pragma unroll
  for (int off = 32; off; off >>= 1){ s += __shfl_xor(s, off); ss += __shfl_xor(ss, off); }
  __shared__ float red[8];
  if (lane == 0){ red[wv] = s; red[4 + wv] = ss; }
  __syncthreads();
  s  = red[0] + red[1] + red[2] + red[3];
  ss = red[4] + red[5] + red[6] + red[7];
  float mean = s * (1.0f / Dz);
  float var  = ss * (1.0f / Dz) - mean * mean;
  float rstd = rsqrtf(var + 1e-5f);
  float4 wg = ((const float4*)w)[tid];
  float4 bg = ((const float4*)b)[tid];
  ushort4 ov;
  ov.x = f2bf((v.x - mean) * rstd * wg.x + bg.x);
  ov.y = f2bf((v.y - mean) * rstd * wg.y + bg.y);
  ov.z = f2bf((v.z - mean) * rstd * wg.z + bg.z);
  ov.w = f2bf((v.w - mean) * rstd * wg.w + bg.w);
  *((ushort4*)(out + (long)row * Dz) + tid) = ov;
}

// ---------------- GEMM: C = A(MxK,bf16) @ Bt(NxK,bf16)^T ---------------------
// MODE 0: Cf fp32   MODE 1: Cf = acc + addsrc   MODE 2: Cb = bf16(gelu(acc))
// MODE 3: Cb = bf16(acc).  Batched via blockIdx.z with element strides.
template<int MODE>
__global__ __launch_bounds__(256) void k_gemm(
    const unsigned short* __restrict__ A,
    const unsigned short* __restrict__ Bt,
    float* __restrict__ Cf, unsigned short* __restrict__ Cb,
    const float* __restrict__ addsrc,
    int M, int N, int K, long sA, long sB, long sC)
{
  __shared__ unsigned short As[128][72];
  __shared__ unsigned short Bs[128][72];
  A  += (long)blockIdx.z * sA;
  Bt += (long)blockIdx.z * sB;
  int bm = blockIdx.y * 128, bn = blockIdx.x * 128;
  int tid = threadIdx.x, wv = tid >> 6, lane = tid & 63;
  int wr = (wv >> 1) * 64, wc = (wv & 1) * 64;
  f4v acc[4][4];
  #pragma unroll
  for (int m = 0; m < 4; ++m)
    #pragma unroll
    for (int n = 0; n < 4; ++n)
      acc[m][n] = (f4v){0.f, 0.f, 0.f, 0.f};

  int sr = tid >> 3, scc = (tid & 7) * 8;
  const unsigned short* Ag = A  + (long)(bm + sr) * K + scc;
  const unsigned short* Bg = Bt + (long)(bn + sr) * K + scc;

  for (int k0 = 0; k0 < K; k0 += 64) {
    uint4 av[4], bv[4];
    #pragma unroll
    for (int p = 0; p < 4; ++p) {
      av[p] = *(const uint4*)(Ag + k0 + (long)p * 32 * K);
      bv[p] = *(const uint4*)(Bg + k0 + (long)p * 32 * K);
    }
    __syncthreads();
    #pragma unroll
    for (int p = 0; p < 4; ++p) {
      *(uint4*)&As[sr + p * 32][scc] = av[p];
      *(uint4*)&Bs[sr + p * 32][scc] = bv[p];
    }
    __syncthreads();
    #pragma unroll
    for (int kk = 0; kk < 64; kk += 32) {
      s8v af[4], bfv[4];
      int fr = lane & 15, kg = kk + (lane >> 4) * 8;
      #pragma unroll
      for (int m = 0; m < 4; ++m) af[m]  = *(const s8v*)&As[wr + m * 16 + fr][kg];
      #pragma unroll
      for (int n = 0; n < 4; ++n) bfv[n] = *(const s8v*)&Bs[wc + n * 16 + fr][kg];
      #pragma unroll
      for (int m = 0; m < 4; ++m)
        #pragma unroll
        for (int n = 0; n < 4; ++n)
          acc[m][n] = __builtin_amdgcn_mfma_f32_16x16x32_bf16(af[m], bfv[n], acc[m][n], 0, 0, 0);
    }
  }
  int cr0 = bm + wr + (lane >> 4) * 4;
  int cc0 = bn + wc + (lane & 15);
  #pragma unroll
  for (int m = 0; m < 4; ++m)
    #pragma unroll
    for (int n = 0; n < 4; ++n)
      #pragma unroll
      for (int i = 0; i < 4; ++i) {
        long row = cr0 + m * 16 + i, col = cc0 + n * 16;
        long idx = (long)blockIdx.z * sC + row * (long)N + col;
        float v = acc[m][n][i];
        if (MODE == 1) v += addsrc[idx];
        if (MODE == 2) v = gelu_f(v);
        if (MODE <= 1) Cf[idx] = v; else Cb[idx] = f2bf(v);
      }
}

// ---------------- RoPE in-place on qkv fp32 ----------------------------------
__global__ __launch_bounds__(256) void k_rope(float* __restrict__ qkv)
{
  int gid = blockIdx.x * 256 + threadIdx.x;   // B*T*H*32 total
  int j = gid & 31;
  int h = (gid >> 5) & (Hz - 1);
  int t = (gid >> 9) & (Tz - 1);
  int b = gid >> 19;
  float inv = exp2f(-(float)j * 0.41524101186092030f);  // 10000^(-2j/64)
  float ang = (float)t * inv;
  float sn, cs;
  sincosf(ang, &sn, &cs);
  long base = ((long)(b * Tz + t)) * 3072 + h * 64 + j;
  float q1 = qkv[base], q2 = qkv[base + 32];
  qkv[base]      = q1 * cs - q2 * sn;
  qkv[base + 32] = q1 * sn + q2 * cs;
  long kb = base + 1024;
  float k1 = qkv[kb], k2 = qkv[kb + 32];
  qkv[kb]      = k1 * cs - k2 * sn;
  qkv[kb + 32] = k1 * sn + k2 * cs;
}

// ---------------- backbone flash attention (hd=64) ---------------------------
// block = 4 waves; wave handles 4 q-rows; 16 rows/block share K/V LDS tiles.
__global__ __launch_bounds__(256) void k_attn_bb(const float* __restrict__ qkv,
    unsigned short* __restrict__ ao)
{
  int nbt = Tz / 16;
  int bh = blockIdx.x / nbt, t0 = (blockIdx.x % nbt) * 16;
  int b = bh >> 4, h = bh & 15;
  int tid = threadIdx.x, wv = tid >> 6, lane = tid & 63;
  __shared__ float Ks[64][65], Vs[64][65];
  __shared__ float q_s[16][64];
  __shared__ float p_s[16][64];
  {
    int r = tid >> 4, c4 = (tid & 15) * 4;
    const float* qp = qkv + ((long)(b * Tz + t0 + r)) * 3072 + h * 64 + c4;
    float4 qv = *(const float4*)qp;
    qv.x *= 0.125f; qv.y *= 0.125f; qv.z *= 0.125f; qv.w *= 0.125f;
    *(float4*)&q_s[r][c4] = qv;
  }
  float m[4], l[4], o[4];
  #pragma unroll
  for (int r = 0; r < 4; ++r){ m[r] = -1e30f; l[r] = 0.f; o[r] = 0.f; }
  int tmaxr = t0 + 15;
  for (int kt0 = 0; kt0 <= tmaxr; kt0 += 64) {
    __syncthreads();
    {
      int key = tid >> 2, c0 = (tid & 3) * 16;
      const float* kp = qkv + ((long)(b * Tz + kt0 + key)) * 3072 + 1024 + h * 64 + c0;
      #pragma unroll
      for (int i = 0; i < 4; ++i) {
        float4 kv4 = *(const float4*)(kp + i * 4);
        float4 vv4 = *(const float4*)(kp + 1024 + i * 4);
        Ks[key][c0 + i*4 + 0] = kv4.x; Ks[key][c0 + i*4 + 1] = kv4.y;
        Ks[key][c0 + i*4 + 2] = kv4.z; Ks[key][c0 + i*4 + 3] = kv4.w;
        Vs[key][c0 + i*4 + 0] = vv4.x; Vs[key][c0 + i*4 + 1] = vv4.y;
        Vs[key][c0 + i*4 + 2] = vv4.z; Vs[key][c0 + i*4 + 3] = vv4.w;
      }
    }
    __syncthreads();
    float sc[4] = {0.f, 0.f, 0.f, 0.f};
    #pragma unroll
    for (int d4 = 0; d4 < 64; d4 += 4) {
      float ka = Ks[lane][d4 + 0], kb2 = Ks[lane][d4 + 1];
      float kc = Ks[lane][d4 + 2], kd  = Ks[lane][d4 + 3];
      #pragma unroll
      for (int r = 0; r < 4; ++r) {
        float4 q4 = *(const float4*)&q_s[wv * 4 + r][d4];
        sc[r] = fmaf(q4.x, ka, sc[r]); sc[r] = fmaf(q4.y, kb2, sc[r]);
        sc[r] = fmaf(q4.z, kc, sc[r]); sc[r] = fmaf(q4.w, kd,  sc[r]);
      }
    }
    #pragma unroll
    for (int r = 0; r < 4; ++r) {
      int t = t0 + wv * 4 + r;
      if (kt0 > t) continue;
      float sv = (kt0 + lane <= t) ? sc[r] : -1e30f;
      float tm = sv;
      #pragma unroll
      for (int off = 32; off; off >>= 1) tm = fmaxf(tm, __shfl_xor(tm, off));
      float mnew = fmaxf(m[r], tm);
      float p = __expf(sv - mnew);
      float psum = p;
      #pragma unroll
      for (int off = 32; off; off >>= 1) psum += __shfl_xor(psum, off);
      float alpha = __expf(m[r] - mnew);
      l[r] = l[r] * alpha + psum;
      o[r] *= alpha;
      m[r] = mnew;
      p_s[wv * 4 + r][lane] = p;
    }
    #pragma unroll
    for (int k4 = 0; k4 < 64; k4 += 4) {
      float va = Vs[k4 + 0][lane], vb = Vs[k4 + 1][lane];
      float vc = Vs[k4 + 2][lane], vd = Vs[k4 + 3][lane];
      #pragma unroll
      for (int r = 0; r < 4; ++r) {
        int t = t0 + wv * 4 + r;
        if (kt0 > t) continue;
        float4 p4 = *(const float4*)&p_s[wv * 4 + r][k4];
        o[r] = fmaf(p4.x, va, o[r]); o[r] = fmaf(p4.y, vb, o[r]);
        o[r] = fmaf(p4.z, vc, o[r]); o[r] = fmaf(p4.w, vd, o[r]);
      }
    }
  }
  #pragma unroll
  for (int r = 0; r < 4; ++r) {
    int t = t0 + wv * 4 + r;
    ao[((long)(b * Tz + t)) * Dz + h * 64 + lane] = f2bf(o[r] / l[r]);
  }
}

// ---------------- router: softmax(h @ router_w) ------------------------------
__global__ __launch_bounds__(256) void k_router(const unsigned short* __restrict__ h,
    const float* __restrict__ rw, float* __restrict__ rout)
{
  int row = blockIdx.x, tid = threadIdx.x;
  float a0 = 0.f, a1 = 0.f, a2 = 0.f, a3 = 0.f;
  const unsigned short* hp = h + (long)row * Dz;
  for (int d = tid; d < Dz; d += 256) {
    float hv = bf2f(hp[d]);
    float4 w4 = *(const float4*)(rw + d * 4);
    a0 = fmaf(hv, w4.x, a0); a1 = fmaf(hv, w4.y, a1);
    a2 = fmaf(hv, w4.z, a2); a3 = fmaf(hv, w4.w, a3);
  }
  int lane = tid & 63, wv = tid >> 6;
  #pragma unroll
  for (int off = 32; off; off >>= 1) {
    a0 += __shfl_xor(a0, off); a1 += __shfl_xor(a1, off);
    a2 += __shfl_xor(a2, off); a3 += __shfl_xor(a3, off);
  }
  __shared__ float red[4][4];
  if (lane == 0){ red[wv][0] = a0; red[wv][1] = a1; red[wv][2] = a2; red[wv][3] = a3; }
  __syncthreads();
  if (tid == 0) {
    float s0 = red[0][0] + red[1][0] + red[2][0] + red[3][0];
    float s1 = red[0][1] + red[1][1] + red[2][1] + red[3][1];
    float s2 = red[0][2] + red[1][2] + red[2][2] + red[3][2];
    float s3 = red[0][3] + red[1][3] + red[2][3] + red[3][3];
    float mx = fmaxf(fmaxf(s0, s1), fmaxf(s2, s3));
    float e0 = __expf(s0 - mx), e1 = __expf(s1 - mx);
    float e2 = __expf(s2 - mx), e3 = __expf(s3 - mx);
    float inv = 1.0f / (e0 + e1 + e2 + e3);
    float4 r = {e0 * inv, e1 * inv, e2 * inv, e3 * inv};
    *(float4*)(rout + (long)row * 4) = r;
  }
}

// ---------------- causal softmax (attn2): S fp32 -> P bf16 -------------------
__global__ __launch_bounds__(256) void k_softmax_causal(const float* __restrict__ S,
    unsigned short* __restrict__ P, float scale)
{
  long row = blockIdx.x;
  int t = (int)(row & (Tz - 1));
  int tid = threadIdx.x;
  const float* sp = S + row * Tz;
  float4 v = *(const float4*)(sp + tid * 4);
  float vv[4];
  vv[0] = (tid*4 + 0 <= t) ? v.x * scale : -1e30f;
  vv[1] = (tid*4 + 1 <= t) ? v.y * scale : -1e30f;
  vv[2] = (tid*4 + 2 <= t) ? v.z * scale : -1e30f;
  vv[3] = (tid*4 + 3 <= t) ? v.w * scale : -1e30f;
  float mx = fmaxf(fmaxf(vv[0], vv[1]), fmaxf(vv[2], vv[3]));
  int lane = tid & 63, wv = tid >> 6;
  #pragma unroll
  for (int off = 32; off; off >>= 1) mx = fmaxf(mx, __shfl_xor(mx, off));
  __shared__ float red[8];
  if (lane == 0) red[wv] = mx;
  __syncthreads();
  mx = fmaxf(fmaxf(red[0], red[1]), fmaxf(red[2], red[3]));
  float p[4];
  float s = 0.f;
  #pragma unroll
  for (int i = 0; i < 4; ++i){ p[i] = __expf(vv[i] - mx); s += p[i]; }
  #pragma unroll
  for (int off = 32; off; off >>= 1) s += __shfl_xor(s, off);
  if (lane == 0) red[4 + wv] = s;
  __syncthreads();
  s = red[4] + red[5] + red[6] + red[7];
  float inv = 1.0f / s;
  ushort4 ov;
  ov.x = f2bf(p[0] * inv); ov.y = f2bf(p[1] * inv);
  ov.z = f2bf(p[2] * inv); ov.w = f2bf(p[3] * inv);
  *((ushort4*)(P + row * Tz) + tid) = ov;
}

// ---------------- fused conv tier + combine + sink scale ---------------------
__global__ __launch_bounds__(256) void k_combine(
    const float* __restrict__ x2, const unsigned short* __restrict__ hbf,
    const float* __restrict__ eo, const float* __restrict__ ap,
    const float* __restrict__ rout, const float* __restrict__ convw,
    const float* __restrict__ tg, const float* __restrict__ sinkp,
    float* __restrict__ outx)
{
  int row = blockIdx.x, tid = threadIdx.x;
  int t = row & (Tz - 1), b = row >> 10;
  int d0 = tid * 4;
  float4 x4 = *(const float4*)(x2 + (long)row * Dz + d0);
  float4 e4 = *(const float4*)(eo + (long)row * Dz + d0);
  float4 a4 = *(const float4*)(ap + (long)row * Dz + d0);
  float4 t4 = *(const float4*)(tg + d0);
  float4 r4 = *(const float4*)(rout + (long)row * 4);
  float sks = fabsf(sinkp[0]);
  float kv = 1.0f - r4.w * (1.0f - sks);
  const float4* cwp = (const float4*)(convw + (long)d0 * 3);
  float4 c0 = cwp[0], c1 = cwp[1], c2 = cwp[2];
  float cwf[12] = {c0.x, c0.y, c0.z, c0.w, c1.x, c1.y, c1.z, c1.w, c2.x, c2.y, c2.z, c2.w};
  float hv[3][4];
  #pragma unroll
  for (int tap = 0; tap < 3; ++tap) {
    int tt = t - 2 + tap;
    if (tt >= 0) {
      ushort4 hu = *((const ushort4*)(hbf + ((long)(b * Tz + tt)) * Dz + d0));
      hv[tap][0] = bf2f(hu.x); hv[tap][1] = bf2f(hu.y);
      hv[tap][2] = bf2f(hu.z); hv[tap][3] = bf2f(hu.w);
    } else {
      hv[tap][0] = 0.f; hv[tap][1] = 0.f; hv[tap][2] = 0.f; hv[tap][3] = 0.f;
    }
  }
  float ov[4];
  float xi[4] = {x4.x, x4.y, x4.z, x4.w};
  float ei[4] = {e4.x, e4.y, e4.z, e4.w};
  float ai[4] = {a4.x, a4.y, a4.z, a4.w};
  float ti[4] = {t4.x, t4.y, t4.z, t4.w};
  #pragma unroll
  for (int i = 0; i < 4; ++i) {
    float conv = hv[0][i] * cwf[i*3 + 0] + hv[1][i] * cwf[i*3 + 1] + hv[2][i] * cwf[i*3 + 2];
    float comb = gelu_f(conv) * r4.x + ei[i] * r4.y + ai[i] * r4.z;
    ov[i] = (xi[i] + comb * ti[i]) * kv;
  }
  float4 res = {ov[0], ov[1], ov[2], ov[3]};
  *(float4*)(outx + (long)row * Dz + d0) = res;
}

// ---------------- host launcher ----------------------------------------------
extern "C" void kernel_launch(void* const* d_in, const int* in_sizes, int n_in,
                              void* d_out, int out_size, void* d_ws, size_t ws_size,
                              hipStream_t stream) {
  (void)in_sizes; (void)n_in; (void)out_size; (void)ws_size;
  const float* x       = (const float*)d_in[0];
  const float* ln1_w   = (const float*)d_in[1];
  const float* ln1_b   = (const float*)d_in[2];
  const float* qkv_w   = (const float*)d_in[3];
  const float* out_w   = (const float*)d_in[4];
  const float* ln2_w   = (const float*)d_in[5];
  const float* ln2_b   = (const float*)d_in[6];
  const float* router_w= (const float*)d_in[7];
  const float* conv_w  = (const float*)d_in[8];
  const float* ew1     = (const float*)d_in[9];
  const float* ew2     = (const float*)d_in[10];
  const float* at_wq   = (const float*)d_in[11];
  const float* at_wk   = (const float*)d_in[12];
  const float* at_wv   = (const float*)d_in[13];
  const float* at_wo   = (const float*)d_in[14];
  const float* tg      = (const float*)d_in[15];
  const float* sinkp   = (const float*)d_in[16];
  float* outx = (float*)d_out;
  float* rout = outx + (size_t)NTz * Dz;

  char* ws = (char*)d_ws;
  size_t off = 0;
  auto alloc = [&](size_t bytes) -> char* {
    char* p = ws + off;
    off += (bytes + 255) & ~(size_t)255;
    return p;
  };
  unsigned short* w_qkvt = (unsigned short*)alloc((size_t)3072*1024*2);
  unsigned short* w_outt = (unsigned short*)alloc((size_t)1024*1024*2);
  unsigned short* w_ew1t = (unsigned short*)alloc((size_t)2048*1024*2);
  unsigned short* w_ew2t = (unsigned short*)alloc((size_t)1024*2048*2);
  unsigned short* w_wqt  = (unsigned short*)alloc((size_t)1024*1024*2);
  unsigned short* w_wkt  = (unsigned short*)alloc((size_t)1024*1024*2);
  unsigned short* w_wvt  = (unsigned short*)alloc((size_t)1024*1024*2);
  unsigned short* w_wot  = (unsigned short*)alloc((size_t)1024*1024*2);
  unsigned short* h1bf   = (unsigned short*)alloc((size_t)NTz*Dz*2);
  char*           slab   = alloc((size_t)NTz*3072*4);       // qkv fp32, later e1/eo/S
  float*          qkvf   = (float*)slab;
  unsigned short* e1bf   = (unsigned short*)slab;                       // 16 MB
  float*          eof_   = (float*)(slab + (size_t)16*1024*1024);       // 16 MB
  float*          Sf     = (float*)(slab + (size_t)32*1024*1024);       // 16 MB
  unsigned short* aobf   = (unsigned short*)alloc((size_t)NTz*Dz*2);
  float*          x2f    = (float*)alloc((size_t)NTz*Dz*4);
  unsigned short* hbf    = (unsigned short*)alloc((size_t)NTz*Dz*2);
  unsigned short* Pbf    = (unsigned short*)alloc((size_t)Bz*Tz*Tz*2);
  unsigned short* q2bf   = (unsigned short*)alloc((size_t)NTz*Dz*2);
  unsigned short* k2bf   = (unsigned short*)alloc((size_t)NTz*Dz*2);
  float*          v2f    = (float*)alloc((size_t)NTz*Dz*4);
  unsigned short* v2tbf  = (unsigned short*)alloc((size_t)NTz*Dz*2);
  unsigned short* a2obf  = (unsigned short*)alloc((size_t)NTz*Dz*2);
  float*          a2pf   = (float*)alloc((size_t)NTz*Dz*4);

  dim3 blk(256);
  const long TD = (long)Tz * Dz, TT = (long)Tz * Tz;

  // weight convert+transpose -> bf16 (N x K)
  k_convtrans<<<dim3(96, 32, 1), blk, 0, stream>>>(qkv_w, w_qkvt, 1024, 3072, 0, 0);
  k_convtrans<<<dim3(32, 32, 1), blk, 0, stream>>>(out_w, w_outt, 1024, 1024, 0, 0);
  k_convtrans<<<dim3(64, 32, 1), blk, 0, stream>>>(ew1,   w_ew1t, 1024, 2048, 0, 0);
  k_convtrans<<<dim3(32, 64, 1), blk, 0, stream>>>(ew2,   w_ew2t, 2048, 1024, 0, 0);
  k_convtrans<<<dim3(32, 32, 1), blk, 0, stream>>>(at_wq, w_wqt,  1024, 1024, 0, 0);
  k_convtrans<<<dim3(32, 32, 1), blk, 0, stream>>>(at_wk, w_wkt,  1024, 1024, 0, 0);
  k_convtrans<<<dim3(32, 32, 1), blk, 0, stream>>>(at_wv, w_wvt,  1024, 1024, 0, 0);
  k_convtrans<<<dim3(32, 32, 1), blk, 0, stream>>>(at_wo, w_wot,  1024, 1024, 0, 0);

  // backbone
  k_layernorm<<<NTz, blk, 0, stream>>>(x, ln1_w, ln1_b, h1bf);
  k_gemm<0><<<dim3(24, 32, 1), blk, 0, stream>>>(h1bf, w_qkvt, qkvf, nullptr, nullptr,
                                                 NTz, 3072, 1024, 0, 0, 0);
  k_rope<<<8192, blk, 0, stream>>>(qkvf);
  k_attn_bb<<<4096, blk, 0, stream>>>(qkvf, aobf);
  k_gemm<1><<<dim3(8, 32, 1), blk, 0, stream>>>(aobf, w_outt, x2f, nullptr, x,
                                                NTz, 1024, 1024, 0, 0, 0);
  // tiers
  k_layernorm<<<NTz, blk, 0, stream>>>(x2f, ln2_w, ln2_b, hbf);
  k_router<<<NTz, blk, 0, stream>>>(hbf, router_w, rout);
  k_gemm<2><<<dim3(16, 32, 1), blk, 0, stream>>>(hbf, w_ew1t, nullptr, e1bf, nullptr,
                                                 NTz, 2048, 1024, 0, 0, 0);
  k_gemm<0><<<dim3(8, 32, 1), blk, 0, stream>>>(e1bf, w_ew2t, eof_, nullptr, nullptr,
                                                NTz, 1024, 2048, 0, 0, 0);
  k_gemm<3><<<dim3(8, 32, 1), blk, 0, stream>>>(hbf, w_wqt, nullptr, q2bf, nullptr,
                                                NTz, 1024, 1024, 0, 0, 0);
  k_gemm<3><<<dim3(8, 32, 1), blk, 0, stream>>>(hbf, w_wkt, nullptr, k2bf, nullptr,
                                                NTz, 1024, 1024, 0, 0, 0);
  k_gemm<0><<<dim3(8, 32, 1), blk, 0, stream>>>(hbf, w_wvt, v2f, nullptr, nullptr,
                                                NTz, 1024, 1024, 0, 0, 0);
  k_convtrans<<<dim3(32, 32, 4), blk, 0, stream>>>(v2f, v2tbf, 1024, 1024, TD, TD);
  k_gemm<0><<<dim3(8, 8, 4), blk, 0, stream>>>(q2bf, k2bf, Sf, nullptr, nullptr,
                                               1024, 1024, 1024, TD, TD, TT);
  k_softmax_causal<<<NTz, blk, 0, stream>>>(Sf, Pbf, 0.03125f);
  k_gemm<3><<<dim3(8, 8, 4), blk, 0, stream>>>(Pbf, v2tbf, nullptr, a2obf, nullptr,
                                               1024, 1024, 1024, TT, TD, TD);
  k_gemm<0><<<dim3(8, 32, 1), blk, 0, stream>>>(a2obf, w_wot, a2pf, nullptr, nullptr,
                                                NTz, 1024, 1024, 0, 0, 0);
  k_combine<<<NTz, blk, 0, stream>>>(x2f, hbf, eof_, a2pf, rout, conv_w, tg, sinkp, outx);
}

// Round 2
// 791.155 us; speedup vs baseline: 2.6192x; 2.6192x over previous
//
#include <hip/hip_runtime.h>

#define Bz 4
#define Tz 1024
#define Dz 1024
#define Hz 16
#define NTz (Bz*Tz)

typedef short s8v __attribute__((ext_vector_type(8)));
typedef float f4v __attribute__((ext_vector_type(4)));

__device__ __forceinline__ float bf2f(unsigned short u){
  unsigned int x = ((unsigned int)u) << 16;
  return __builtin_bit_cast(float, x);
}
__device__ __forceinline__ unsigned short f2bf(float f){
  unsigned int x = __builtin_bit_cast(unsigned int, f);
  x += 0x7fffu + ((x >> 16) & 1u);
  return (unsigned short)(x >> 16);
}
__device__ __forceinline__ float gelu_f(float x){
  float x3 = x*x*x;
  return 0.5f*x*(1.0f + tanhf(0.7978845608028654f*(x + 0.044715f*x3)));
}

// ---------------- convert + transpose: fp32 (R x C) -> bf16 (C x R) ----------
__global__ __launch_bounds__(256) void k_convtrans(const float* __restrict__ in,
    unsigned short* __restrict__ out, int R, int C, long sIn, long sOut)
{
  __shared__ float tile[32][33];
  in  += (long)blockIdx.z * sIn;
  out += (long)blockIdx.z * sOut;
  int c0 = blockIdx.x * 32, r0 = blockIdx.y * 32;
  int tx = threadIdx.x & 31, ty = threadIdx.x >> 5;
  #pragma unroll
  for (int i = 0; i < 32; i += 8)
    tile[ty + i][tx] = in[(long)(r0 + ty + i) * C + c0 + tx];
  __syncthreads();
  #pragma unroll
  for (int i = 0; i < 32; i += 8)
    out[(long)(c0 + ty + i) * R + r0 + tx] = f2bf(tile[tx][ty + i]);
}

// ---------------- layernorm: fp32 in -> bf16 out (row = 1024) ----------------
__global__ __launch_bounds__(256) void k_layernorm(const float* __restrict__ x,
    const float* __restrict__ w, const float* __restrict__ b,
    unsigned short* __restrict__ out)
{
  int row = blockIdx.x, tid = threadIdx.x;
  const float4* xp = (const float4*)(x + (long)row * Dz);
  float4 v = xp[tid];
  float s  = v.x + v.y + v.z + v.w;
  float ss = v.x*v.x + v.y*v.y + v.z*v.z + v.w*v.w;
  int lane = tid & 63, wv = tid >> 6;
  #pragma unroll
  for (int off = 32; off; off >>= 1){ s += __shfl_xor(s, off); ss += __shfl_xor(ss, off); }
  __shared__ float red[8];
  if (lane == 0){ red[wv] = s; red[4 + wv] = ss; }
  __syncthreads();
  s  = red[0] + red[1] + red[2] + red[3];
  ss = red[4] + red[5] + red[6] + red[7];
  float mean = s * (1.0f / Dz);
  float var  = ss * (1.0f / Dz) - mean * mean;
  float rstd = rsqrtf(var + 1e-5f);
  float4 wg = ((const float4*)w)[tid];
  float4 bg = ((const float4*)b)[tid];
  ushort4 ov;
  ov.x = f2bf((v.x - mean) * rstd * wg.x + bg.x);
  ov.y = f2bf((v.y - mean) * rstd * wg.y + bg.y);
  ov.z = f2bf((v.z - mean) * rstd * wg.z + bg.z);
  ov.w = f2bf((v.w - mean) * rstd * wg.w + bg.w);
  *((ushort4*)(out + (long)row * Dz) + tid) = ov;
}

// ---------------- GEMM: C = A(MxK,bf16) @ Bt(NxK,bf16)^T ---------------------
template<int MODE>
__global__ __launch_bounds__(256) void k_gemm(
    const unsigned short* __restrict__ A,
    const unsigned short* __restrict__ Bt,
    float* __restrict__ Cf, unsigned short* __restrict__ Cb,
    const float* __restrict__ addsrc,
    int M, int N, int K, long sA, long sB, long sC)
{
  __shared__ unsigned short As[128][72];
  __shared__ unsigned short Bs[128][72];
  A  += (long)blockIdx.z * sA;
  Bt += (long)blockIdx.z * sB;
  int bm = blockIdx.y * 128, bn = blockIdx.x * 128;
  int tid = threadIdx.x, wv = tid >> 6, lane = tid & 63;
  int wr = (wv >> 1) * 64, wc = (wv & 1) * 64;
  f4v acc[4][4];
  #pragma unroll
  for (int m = 0; m < 4; ++m)
    #pragma unroll
    for (int n = 0; n < 4; ++n)
      acc[m][n] = (f4v){0.f, 0.f, 0.f, 0.f};

  int sr = tid >> 3, scc = (tid & 7) * 8;
  const unsigned short* Ag = A  + (long)(bm + sr) * K + scc;
  const unsigned short* Bg = Bt + (long)(bn + sr) * K + scc;

  for (int k0 = 0; k0 < K; k0 += 64) {
    uint4 av[4], bv[4];
    #pragma unroll
    for (int p = 0; p < 4; ++p) {
      av[p] = *(const uint4*)(Ag + k0 + (long)p * 32 * K);
      bv[p] = *(const uint4*)(Bg + k0 + (long)p * 32 * K);
    }
    __syncthreads();
    #pragma unroll
    for (int p = 0; p < 4; ++p) {
      *(uint4*)&As[sr + p * 32][scc] = av[p];
      *(uint4*)&Bs[sr + p * 32][scc] = bv[p];
    }
    __syncthreads();
    #pragma unroll
    for (int kk = 0; kk < 64; kk += 32) {
      s8v af[4], bfv[4];
      int fr = lane & 15, kg = kk + (lane >> 4) * 8;
      #pragma unroll
      for (int m = 0; m < 4; ++m) af[m]  = *(const s8v*)&As[wr + m * 16 + fr][kg];
      #pragma unroll
      for (int n = 0; n < 4; ++n) bfv[n] = *(const s8v*)&Bs[wc + n * 16 + fr][kg];
      #pragma unroll
      for (int m = 0; m < 4; ++m)
        #pragma unroll
        for (int n = 0; n < 4; ++n)
          acc[m][n] = __builtin_amdgcn_mfma_f32_16x16x32_bf16(af[m], bfv[n], acc[m][n], 0, 0, 0);
    }
  }
  int cr0 = bm + wr + (lane >> 4) * 4;
  int cc0 = bn + wc + (lane & 15);
  #pragma unroll
  for (int m = 0; m < 4; ++m)
    #pragma unroll
    for (int n = 0; n < 4; ++n)
      #pragma unroll
      for (int i = 0; i < 4; ++i) {
        long row = cr0 + m * 16 + i, col = cc0 + n * 16;
        long idx = (long)blockIdx.z * sC + row * (long)N + col;
        float v = acc[m][n][i];
        if (MODE == 1) v += addsrc[idx];
        if (MODE == 2) v = gelu_f(v);
        if (MODE <= 1) Cf[idx] = v; else Cb[idx] = f2bf(v);
      }
}

// ---------------- qkv split: RoPE + bf16 convert + V transpose ---------------
// grid: (T/32, BH). Qb/Kb: [bh][t][64] (Q scaled by 1/8). Vt: [bh][64][t].
__global__ __launch_bounds__(256) void k_qkvsplit(const float* __restrict__ qkv,
    unsigned short* __restrict__ Qb, unsigned short* __restrict__ Kb,
    unsigned short* __restrict__ Vt)
{
  __shared__ unsigned short vt_s[64][40];
  int t0 = blockIdx.x * 32;
  int bh = blockIdx.y;
  int b = bh >> 4, h = bh & 15;
  int tid = threadIdx.x;
  int tl = tid >> 3, jb = (tid & 7) * 4;
  int t = t0 + tl;
  long base = ((long)(b * Tz + t)) * 3072 + h * 64;
  float cs[4], sn[4];
  #pragma unroll
  for (int ii = 0; ii < 4; ++ii) {
    float inv = exp2f(-(float)(jb + ii) * 0.41524101186092030f);
    sincosf((float)t * inv, &sn[ii], &cs[ii]);
  }
  float4 q1 = *(const float4*)(qkv + base + jb);
  float4 q2 = *(const float4*)(qkv + base + jb + 32);
  float4 k1 = *(const float4*)(qkv + base + 1024 + jb);
  float4 k2 = *(const float4*)(qkv + base + 1024 + jb + 32);
  float4 v1 = *(const float4*)(qkv + base + 2048 + jb);
  float4 v2 = *(const float4*)(qkv + base + 2048 + jb + 32);
  float q1a[4] = {q1.x, q1.y, q1.z, q1.w}, q2a[4] = {q2.x, q2.y, q2.z, q2.w};
  float k1a[4] = {k1.x, k1.y, k1.z, k1.w}, k2a[4] = {k2.x, k2.y, k2.z, k2.w};
  float v1a[4] = {v1.x, v1.y, v1.z, v1.w}, v2a[4] = {v2.x, v2.y, v2.z, v2.w};
  unsigned short qo1[4], qo2[4], ko1[4], ko2[4];
  #pragma unroll
  for (int ii = 0; ii < 4; ++ii) {
    qo1[ii] = f2bf((q1a[ii] * cs[ii] - q2a[ii] * sn[ii]) * 0.125f);
    qo2[ii] = f2bf((q1a[ii] * sn[ii] + q2a[ii] * cs[ii]) * 0.125f);
    ko1[ii] = f2bf(k1a[ii] * cs[ii] - k2a[ii] * sn[ii]);
    ko2[ii] = f2bf(k1a[ii] * sn[ii] + k2a[ii] * cs[ii]);
    vt_s[jb + ii][tl]      = f2bf(v1a[ii]);
    vt_s[jb + 32 + ii][tl] = f2bf(v2a[ii]);
  }
  long ob = (long)bh * Tz * 64 + (long)t * 64;
  *(ushort4*)(Qb + ob + jb)      = *(ushort4*)qo1;
  *(ushort4*)(Qb + ob + jb + 32) = *(ushort4*)qo2;
  *(ushort4*)(Kb + ob + jb)      = *(ushort4*)ko1;
  *(ushort4*)(Kb + ob + jb + 32) = *(ushort4*)ko2;
  __syncthreads();
  int d = tid >> 2, tc = (tid & 3) * 8;
  *(uint4*)(Vt + (long)bh * 64 * Tz + (long)d * Tz + t0 + tc) = *(const uint4*)&vt_s[d][tc];
}

// ---------------- backbone flash attention, MFMA (hd=64) ---------------------
// block: 4 waves, QBLK=64 rows of one (b,h); wave w owns rows [w*16, w*16+16).
__global__ __launch_bounds__(256) void k_attn_mfma(
    const unsigned short* __restrict__ Qb, const unsigned short* __restrict__ Kb,
    const unsigned short* __restrict__ Vt, unsigned short* __restrict__ ao)
{
  __shared__ unsigned short Ks[64][72];
  __shared__ unsigned short Vs[64][72];   // Vs[d][key]
  __shared__ unsigned short Ps[4][16][72];
  int qb = blockIdx.x & 15;
  int bh = blockIdx.x >> 4;
  int b = bh >> 4, h = bh & 15;
  int t0 = qb * 64;
  int tid = threadIdx.x, w = tid >> 6, lane = tid & 63;
  int fr = lane & 15, fg = lane >> 4;

  // Q fragments (held in registers for whole kernel)
  const unsigned short* qp = Qb + (long)bh * Tz * 64 + (long)(t0 + w * 16 + fr) * 64 + fg * 8;
  s8v qf[2] = { *(const s8v*)qp, *(const s8v*)(qp + 32) };

  f4v o_acc[4];
  #pragma unroll
  for (int n = 0; n < 4; ++n) o_acc[n] = (f4v){0.f, 0.f, 0.f, 0.f};
  float m_[4] = {-1e30f, -1e30f, -1e30f, -1e30f};
  float l_[4] = {0.f, 0.f, 0.f, 0.f};

  int sr = tid >> 3, sc = (tid & 7) * 8;
  const unsigned short* Kg = Kb + (long)bh * Tz * 64 + (long)sr * 64 + sc;
  const unsigned short* Vg = Vt + (long)bh * 64 * Tz + (long)sr * Tz + sc;

  for (int kt = 0; kt <= qb; ++kt) {
    int k0 = kt * 64;
    __syncthreads();
    *(uint4*)&Ks[sr][sc]      = *(const uint4*)(Kg + (long)k0 * 64);
    *(uint4*)&Ks[sr + 32][sc] = *(const uint4*)(Kg + (long)(k0 + 32) * 64);
    *(uint4*)&Vs[sr][sc]      = *(const uint4*)(Vg + k0);
    *(uint4*)&Vs[sr + 32][sc] = *(const uint4*)(Vg + (long)32 * Tz + k0);
    __syncthreads();

    // S = Q @ K^T  (16 q-rows x 64 keys per wave)
    f4v sacc[4];
    #pragma unroll
    for (int n = 0; n < 4; ++n) sacc[n] = (f4v){0.f, 0.f, 0.f, 0.f};
    #pragma unroll
    for (int kk = 0; kk < 2; ++kk) {
      int kg = kk * 32 + fg * 8;
      #pragma unroll
      for (int n = 0; n < 4; ++n) {
        s8v bf = *(const s8v*)&Ks[n * 16 + fr][kg];
        sacc[n] = __builtin_amdgcn_mfma_f32_16x16x32_bf16(qf[kk], bf, sacc[n], 0, 0, 0);
      }
    }

    // online softmax (lane holds rows i=0..3 at q=fg*4+i, cols n*16+fr)
    bool full = (kt < qb);
    float p[4][4], alpha[4];
    #pragma unroll
    for (int i = 0; i < 4; ++i) {
      int trow = t0 + w * 16 + fg * 4 + i;
      float mx = -1e30f;
      #pragma unroll
      for (int n = 0; n < 4; ++n) {
        float sval = sacc[n][i];
        if (!full) {
          int key = k0 + n * 16 + fr;
          sval = (key <= trow) ? sval : -1e30f;
        }
        p[n][i] = sval;
        mx = fmaxf(mx, sval);
      }
      mx = fmaxf(mx, __shfl_xor(mx, 1));
      mx = fmaxf(mx, __shfl_xor(mx, 2));
      mx = fmaxf(mx, __shfl_xor(mx, 4));
      mx = fmaxf(mx, __shfl_xor(mx, 8));
      float mnew = fmaxf(m_[i], mx);
      alpha[i] = __expf(m_[i] - mnew);
      m_[i] = mnew;
      float ps = 0.f;
      #pragma unroll
      for (int n = 0; n < 4; ++n) {
        float pv = __expf(p[n][i] - mnew);
        p[n][i] = pv;
        ps += pv;
      }
      ps += __shfl_xor(ps, 1); ps += __shfl_xor(ps, 2);
      ps += __shfl_xor(ps, 4); ps += __shfl_xor(ps, 8);
      l_[i] = l_[i] * alpha[i] + ps;
    }
    #pragma unroll
    for (int n = 0; n < 4; ++n)
      #pragma unroll
      for (int i = 0; i < 4; ++i)
        o_acc[n][i] *= alpha[i];
    // stash P (wave-private LDS; no barrier needed)
    #pragma unroll
    for (int n = 0; n < 4; ++n)
      #pragma unroll
      for (int i = 0; i < 4; ++i)
        Ps[w][fg * 4 + i][n * 16 + fr] = f2bf(p[n][i]);

    // O += P @ V  (B-operand from Vs[d][key] = V^T)
    #pragma unroll
    for (int kk = 0; kk < 2; ++kk) {
      int kg = kk * 32 + fg * 8;
      s8v pa = *(const s8v*)&Ps[w][fr][kg];
      #pragma unroll
      for (int n = 0; n < 4; ++n) {
        s8v vb = *(const s8v*)&Vs[n * 16 + fr][kg];
        o_acc[n] = __builtin_amdgcn_mfma_f32_16x16x32_bf16(pa, vb, o_acc[n], 0, 0, 0);
      }
    }
  }

  float inv[4];
  #pragma unroll
  for (int i = 0; i < 4; ++i) inv[i] = 1.0f / l_[i];
  #pragma unroll
  for (int n = 0; n < 4; ++n)
    #pragma unroll
    for (int i = 0; i < 4; ++i) {
      int t = t0 + w * 16 + fg * 4 + i;
      ao[((long)(b * Tz + t)) * Dz + h * 64 + n * 16 + fr] = f2bf(o_acc[n][i] * inv[i]);
    }
}

// ---------------- router: softmax(h @ router_w) ------------------------------
__global__ __launch_bounds__(256) void k_router(const unsigned short* __restrict__ h,
    const float* __restrict__ rw, float* __restrict__ rout)
{
  int row = blockIdx.x, tid = threadIdx.x;
  float a0 = 0.f, a1 = 0.f, a2 = 0.f, a3 = 0.f;
  const unsigned short* hp = h + (long)row * Dz;
  for (int d = tid; d < Dz; d += 256) {
    float hv = bf2f(hp[d]);
    float4 w4 = *(const float4*)(rw + d * 4);
    a0 = fmaf(hv, w4.x, a0); a1 = fmaf(hv, w4.y, a1);
    a2 = fmaf(hv, w4.z, a2); a3 = fmaf(hv, w4.w, a3);
  }
  int lane = tid & 63, wv = tid >> 6;
  #pragma unroll
  for (int off = 32; off; off >>= 1) {
    a0 += __shfl_xor(a0, off); a1 += __shfl_xor(a1, off);
    a2 += __shfl_xor(a2, off); a3 += __shfl_xor(a3, off);
  }
  __shared__ float red[4][4];
  if (lane == 0){ red[wv][0] = a0; red[wv][1] = a1; red[wv][2] = a2; red[wv][3] = a3; }
  __syncthreads();
  if (tid == 0) {
    float s0 = red[0][0] + red[1][0] + red[2][0] + red[3][0];
    float s1 = red[0][1] + red[1][1] + red[2][1] + red[3][1];
    float s2 = red[0][2] + red[1][2] + red[2][2] + red[3][2];
    float s3 = red[0][3] + red[1][3] + red[2][3] + red[3][3];
    float mx = fmaxf(fmaxf(s0, s1), fmaxf(s2, s3));
    float e0 = __expf(s0 - mx), e1 = __expf(s1 - mx);
    float e2 = __expf(s2 - mx), e3 = __expf(s3 - mx);
    float inv = 1.0f / (e0 + e1 + e2 + e3);
    float4 r = {e0 * inv, e1 * inv, e2 * inv, e3 * inv};
    *(float4*)(rout + (long)row * 4) = r;
  }
}

// ---------------- causal softmax (attn2): S fp32 -> P bf16 -------------------
__global__ __launch_bounds__(256) void k_softmax_causal(const float* __restrict__ S,
    unsigned short* __restrict__ P, float scale)
{
  long row = blockIdx.x;
  int t = (int)(row & (Tz - 1));
  int tid = threadIdx.x;
  const float* sp = S + row * Tz;
  float4 v = *(const float4*)(sp + tid * 4);
  float vv[4];
  vv[0] = (tid*4 + 0 <= t) ? v.x * scale : -1e30f;
  vv[1] = (tid*4 + 1 <= t) ? v.y * scale : -1e30f;
  vv[2] = (tid*4 + 2 <= t) ? v.z * scale : -1e30f;
  vv[3] = (tid*4 + 3 <= t) ? v.w * scale : -1e30f;
  float mx = fmaxf(fmaxf(vv[0], vv[1]), fmaxf(vv[2], vv[3]));
  int lane = tid & 63, wv = tid >> 6;
  #pragma unroll
  for (int off = 32; off; off >>= 1) mx = fmaxf(mx, __shfl_xor(mx, off));
  __shared__ float red[8];
  if (lane == 0) red[wv] = mx;
  __syncthreads();
  mx = fmaxf(fmaxf(red[0], red[1]), fmaxf(red[2], red[3]));
  float p[4];
  float s = 0.f;
  #pragma unroll
  for (int i = 0; i < 4; ++i){ p[i] = __expf(vv[i] - mx); s += p[i]; }
  #pragma unroll
  for (int off = 32; off; off >>= 1) s += __shfl_xor(s, off);
  if (lane == 0) red[4 + wv] = s;
  __syncthreads();
  s = red[4] + red[5] + red[6] + red[7];
  float inv = 1.0f / s;
  ushort4 ov;
  ov.x = f2bf(p[0] * inv); ov.y = f2bf(p[1] * inv);
  ov.z = f2bf(p[2] * inv); ov.w = f2bf(p[3] * inv);
  *((ushort4*)(P + row * Tz) + tid) = ov;
}

// ---------------- fused conv tier + combine + sink scale ---------------------
__global__ __launch_bounds__(256) void k_combine(
    const float* __restrict__ x2, const unsigned short* __restrict__ hbf,
    const float* __restrict__ eo, const float* __restrict__ ap,
    const float* __restrict__ rout, const float* __restrict__ convw,
    const float* __restrict__ tg, const float* __restrict__ sinkp,
    float* __restrict__ outx)
{
  int row = blockIdx.x, tid = threadIdx.x;
  int t = row & (Tz - 1), b = row >> 10;
  int d0 = tid * 4;
  float4 x4 = *(const float4*)(x2 + (long)row * Dz + d0);
  float4 e4 = *(const float4*)(eo + (long)row * Dz + d0);
  float4 a4 = *(const float4*)(ap + (long)row * Dz + d0);
  float4 t4 = *(const float4*)(tg + d0);
  float4 r4 = *(const float4*)(rout + (long)row * 4);
  float sks = fabsf(sinkp[0]);
  float kv = 1.0f - r4.w * (1.0f - sks);
  const float4* cwp = (const float4*)(convw + (long)d0 * 3);
  float4 c0 = cwp[0], c1 = cwp[1], c2 = cwp[2];
  float cwf[12] = {c0.x, c0.y, c0.z, c0.w, c1.x, c1.y, c1.z, c1.w, c2.x, c2.y, c2.z, c2.w};
  float hv[3][4];
  #pragma unroll
  for (int tap = 0; tap < 3; ++tap) {
    int tt = t - 2 + tap;
    if (tt >= 0) {
      ushort4 hu = *((const ushort4*)(hbf + ((long)(b * Tz + tt)) * Dz + d0));
      hv[tap][0] = bf2f(hu.x); hv[tap][1] = bf2f(hu.y);
      hv[tap][2] = bf2f(hu.z); hv[tap][3] = bf2f(hu.w);
    } else {
      hv[tap][0] = 0.f; hv[tap][1] = 0.f; hv[tap][2] = 0.f; hv[tap][3] = 0.f;
    }
  }
  float ov[4];
  float xi[4] = {x4.x, x4.y, x4.z, x4.w};
  float ei[4] = {e4.x, e4.y, e4.z, e4.w};
  float ai[4] = {a4.x, a4.y, a4.z, a4.w};
  float ti[4] = {t4.x, t4.y, t4.z, t4.w};
  #pragma unroll
  for (int i = 0; i < 4; ++i) {
    float conv = hv[0][i] * cwf[i*3 + 0] + hv[1][i] * cwf[i*3 + 1] + hv[2][i] * cwf[i*3 + 2];
    float comb = gelu_f(conv) * r4.x + ei[i] * r4.y + ai[i] * r4.z;
    ov[i] = (xi[i] + comb * ti[i]) * kv;
  }
  float4 res = {ov[0], ov[1], ov[2], ov[3]};
  *(float4*)(outx + (long)row * Dz + d0) = res;
}

// ---------------- host launcher ----------------------------------------------
extern "C" void kernel_launch(void* const* d_in, const int* in_sizes, int n_in,
                              void* d_out, int out_size, void* d_ws, size_t ws_size,
                              hipStream_t stream) {
  (void)in_sizes; (void)n_in; (void)out_size; (void)ws_size;
  const float* x       = (const float*)d_in[0];
  const float* ln1_w   = (const float*)d_in[1];
  const float* ln1_b   = (const float*)d_in[2];
  const float* qkv_w   = (const float*)d_in[3];
  const float* out_w   = (const float*)d_in[4];
  const float* ln2_w   = (const float*)d_in[5];
  const float* ln2_b   = (const float*)d_in[6];
  const float* router_w= (const float*)d_in[7];
  const float* conv_w  = (const float*)d_in[8];
  const float* ew1     = (const float*)d_in[9];
  const float* ew2     = (const float*)d_in[10];
  const float* at_wq   = (const float*)d_in[11];
  const float* at_wk   = (const float*)d_in[12];
  const float* at_wv   = (const float*)d_in[13];
  const float* at_wo   = (const float*)d_in[14];
  const float* tg      = (const float*)d_in[15];
  const float* sinkp   = (const float*)d_in[16];
  float* outx = (float*)d_out;
  float* rout = outx + (size_t)NTz * Dz;

  char* ws = (char*)d_ws;
  size_t off = 0;
  auto alloc = [&](size_t bytes) -> char* {
    char* p = ws + off;
    off += (bytes + 255) & ~(size_t)255;
    return p;
  };
  unsigned short* w_qkvt = (unsigned short*)alloc((size_t)3072*1024*2);
  unsigned short* w_outt = (unsigned short*)alloc((size_t)1024*1024*2);
  unsigned short* w_ew1t = (unsigned short*)alloc((size_t)2048*1024*2);
  unsigned short* w_ew2t = (unsigned short*)alloc((size_t)1024*2048*2);
  unsigned short* w_wqt  = (unsigned short*)alloc((size_t)1024*1024*2);
  unsigned short* w_wkt  = (unsigned short*)alloc((size_t)1024*1024*2);
  unsigned short* w_wvt  = (unsigned short*)alloc((size_t)1024*1024*2);
  unsigned short* w_wot  = (unsigned short*)alloc((size_t)1024*1024*2);
  unsigned short* h1bf   = (unsigned short*)alloc((size_t)NTz*Dz*2);
  char*           slab   = alloc((size_t)NTz*3072*4);       // qkv fp32, later e1/eo/S
  float*          qkvf   = (float*)slab;
  unsigned short* e1bf   = (unsigned short*)slab;                       // 16 MB
  float*          eof_   = (float*)(slab + (size_t)16*1024*1024);       // 16 MB
  float*          Sf     = (float*)(slab + (size_t)32*1024*1024);       // 16 MB
  unsigned short* aobf   = (unsigned short*)alloc((size_t)NTz*Dz*2);
  float*          x2f    = (float*)alloc((size_t)NTz*Dz*4);
  unsigned short* hbf    = (unsigned short*)alloc((size_t)NTz*Dz*2);
  unsigned short* Pbf    = (unsigned short*)alloc((size_t)Bz*Tz*Tz*2);
  unsigned short* q2bf   = (unsigned short*)alloc((size_t)NTz*Dz*2);
  unsigned short* k2bf   = (unsigned short*)alloc((size_t)NTz*Dz*2);
  float*          v2f    = (float*)alloc((size_t)NTz*Dz*4);
  unsigned short* v2tbf  = (unsigned short*)alloc((size_t)NTz*Dz*2);
  unsigned short* a2obf  = (unsigned short*)alloc((size_t)NTz*Dz*2);
  float*          a2pf   = (float*)alloc((size_t)NTz*Dz*4);

  // attention scratch aliased into buffers only written AFTER attention:
  unsigned short* Qb = (unsigned short*)x2f;   // 8 MB needed, 16 MB available
  unsigned short* Kb = (unsigned short*)q2bf;  // 8 MB (q2bf region)
  unsigned short* Vt = (unsigned short*)v2f;   // 8 MB needed, 16 MB available

  dim3 blk(256);
  const long TD = (long)Tz * Dz, TT = (long)Tz * Tz;

  // weight convert+transpose -> bf16 (N x K)
  k_convtrans<<<dim3(96, 32, 1), blk, 0, stream>>>(qkv_w, w_qkvt, 1024, 3072, 0, 0);
  k_convtrans<<<dim3(32, 32, 1), blk, 0, stream>>>(out_w, w_outt, 1024, 1024, 0, 0);
  k_convtrans<<<dim3(64, 32, 1), blk, 0, stream>>>(ew1,   w_ew1t, 1024, 2048, 0, 0);
  k_convtrans<<<dim3(32, 64, 1), blk, 0, stream>>>(ew2,   w_ew2t, 2048, 1024, 0, 0);
  k_convtrans<<<dim3(32, 32, 1), blk, 0, stream>>>(at_wq, w_wqt,  1024, 1024, 0, 0);
  k_convtrans<<<dim3(32, 32, 1), blk, 0, stream>>>(at_wk, w_wkt,  1024, 1024, 0, 0);
  k_convtrans<<<dim3(32, 32, 1), blk, 0, stream>>>(at_wv, w_wvt,  1024, 1024, 0, 0);
  k_convtrans<<<dim3(32, 32, 1), blk, 0, stream>>>(at_wo, w_wot,  1024, 1024, 0, 0);

  // backbone
  k_layernorm<<<NTz, blk, 0, stream>>>(x, ln1_w, ln1_b, h1bf);
  k_gemm<0><<<dim3(24, 32, 1), blk, 0, stream>>>(h1bf, w_qkvt, qkvf, nullptr, nullptr,
                                                 NTz, 3072, 1024, 0, 0, 0);
  k_qkvsplit<<<dim3(32, 64, 1), blk, 0, stream>>>(qkvf, Qb, Kb, Vt);
  k_attn_mfma<<<dim3(1024, 1, 1), blk, 0, stream>>>(Qb, Kb, Vt, aobf);
  k_gemm<1><<<dim3(8, 32, 1), blk, 0, stream>>>(aobf, w_outt, x2f, nullptr, x,
                                                NTz, 1024, 1024, 0, 0, 0);
  // tiers
  k_layernorm<<<NTz, blk, 0, stream>>>(x2f, ln2_w, ln2_b, hbf);
  k_router<<<NTz, blk, 0, stream>>>(hbf, router_w, rout);
  k_gemm<2><<<dim3(16, 32, 1), blk, 0, stream>>>(hbf, w_ew1t, nullptr, e1bf, nullptr,
                                                 NTz, 2048, 1024, 0, 0, 0);
  k_gemm<0><<<dim3(8, 32, 1), blk, 0, stream>>>(e1bf, w_ew2t, eof_, nullptr, nullptr,
                                                NTz, 1024, 2048, 0, 0, 0);
  k_gemm<3><<<dim3(8, 32, 1), blk, 0, stream>>>(hbf, w_wqt, nullptr, q2bf, nullptr,
                                                NTz, 1024, 1024, 0, 0, 0);
  k_gemm<3><<<dim3(8, 32, 1), blk, 0, stream>>>(hbf, w_wkt, nullptr, k2bf, nullptr,
                                                NTz, 1024, 1024, 0, 0, 0);
  k_gemm<0><<<dim3(8, 32, 1), blk, 0, stream>>>(hbf, w_wvt, v2f, nullptr, nullptr,
                                                NTz, 1024, 1024, 0, 0, 0);
  k_convtrans<<<dim3(32, 32, 4), blk, 0, stream>>>(v2f, v2tbf, 1024, 1024, TD, TD);
  k_gemm<0><<<dim3(8, 8, 4), blk, 0, stream>>>(q2bf, k2bf, Sf, nullptr, nullptr,
                                               1024, 1024, 1024, TD, TD, TT);
  k_softmax_causal<<<NTz, blk, 0, stream>>>(Sf, Pbf, 0.03125f);
  k_gemm<3><<<dim3(8, 8, 4), blk, 0, stream>>>(Pbf, v2tbf, nullptr, a2obf, nullptr,
                                               1024, 1024, 1024, TT, TD, TD);
  k_gemm<0><<<dim3(8, 32, 1), blk, 0, stream>>>(a2obf, w_wot, a2pf, nullptr, nullptr,
                                                NTz, 1024, 1024, 0, 0, 0);
  k_combine<<<NTz, blk, 0, stream>>>(x2f, hbf, eof_, a2pf, rout, conv_w, tg, sinkp, outx);
}

// Round 3
// 414.048 us; speedup vs baseline: 5.0047x; 1.9108x over previous
//
#include <hip/hip_runtime.h>

#define Bz 4
#define Tz 1024
#define Dz 1024
#define Hz 16
#define NTz (Bz*Tz)

typedef short s8v __attribute__((ext_vector_type(8)));
typedef float f4v __attribute__((ext_vector_type(4)));

__device__ __forceinline__ float bf2f(unsigned short u){
  unsigned int x = ((unsigned int)u) << 16;
  return __builtin_bit_cast(float, x);
}
__device__ __forceinline__ unsigned short f2bf(float f){
  unsigned int x = __builtin_bit_cast(unsigned int, f);
  x += 0x7fffu + ((x >> 16) & 1u);
  return (unsigned short)(x >> 16);
}
__device__ __forceinline__ float gelu_f(float x){
  float x3 = x*x*x;
  return 0.5f*x*(1.0f + tanhf(0.7978845608028654f*(x + 0.044715f*x3)));
}
// async global->LDS, 16B per lane; lds base must be wave-uniform
__device__ __forceinline__ void gl16(const unsigned short* g, unsigned short* l){
  __builtin_amdgcn_global_load_lds(
      (const __attribute__((address_space(1))) unsigned int*)g,
      (__attribute__((address_space(3))) unsigned int*)l, 16, 0, 0);
}

// ---------------- convert + transpose: fp32 (R x C) -> bf16 (C x R) ----------
__global__ __launch_bounds__(256) void k_convtrans(const float* __restrict__ in,
    unsigned short* __restrict__ out, int R, int C)
{
  __shared__ float tile[32][33];
  int c0 = blockIdx.x * 32, r0 = blockIdx.y * 32;
  int tx = threadIdx.x & 31, ty = threadIdx.x >> 5;
  #pragma unroll
  for (int i = 0; i < 32; i += 8)
    tile[ty + i][tx] = in[(long)(r0 + ty + i) * C + c0 + tx];
  __syncthreads();
  #pragma unroll
  for (int i = 0; i < 32; i += 8)
    out[(long)(c0 + ty + i) * R + r0 + tx] = f2bf(tile[tx][ty + i]);
}

// ---- bf16 strided transpose: in[r*ld + c] (1024 cols) -> out[c*1024 + r] ----
__global__ __launch_bounds__(256) void k_convtrans_b(const unsigned short* __restrict__ in,
    unsigned short* __restrict__ out, int ld, long sIn, long sOut)
{
  __shared__ unsigned short tile[32][34];
  in  += (long)blockIdx.z * sIn;
  out += (long)blockIdx.z * sOut;
  int c0 = blockIdx.x * 32, r0 = blockIdx.y * 32;
  int tx = threadIdx.x & 31, ty = threadIdx.x >> 5;
  #pragma unroll
  for (int i = 0; i < 32; i += 8)
    tile[ty + i][tx] = in[(long)(r0 + ty + i) * ld + c0 + tx];
  __syncthreads();
  #pragma unroll
  for (int i = 0; i < 32; i += 8)
    out[(long)(c0 + ty + i) * 1024 + r0 + tx] = tile[tx][ty + i];
}

// ---------------- layernorm: fp32 in -> bf16 out (row = 1024) ----------------
__global__ __launch_bounds__(256) void k_layernorm(const float* __restrict__ x,
    const float* __restrict__ w, const float* __restrict__ b,
    unsigned short* __restrict__ out)
{
  int row = blockIdx.x, tid = threadIdx.x;
  const float4* xp = (const float4*)(x + (long)row * Dz);
  float4 v = xp[tid];
  float s  = v.x + v.y + v.z + v.w;
  float ss = v.x*v.x + v.y*v.y + v.z*v.z + v.w*v.w;
  int lane = tid & 63, wv = tid >> 6;
  #pragma unroll
  for (int off = 32; off; off >>= 1){ s += __shfl_xor(s, off); ss += __shfl_xor(ss, off); }
  __shared__ float red[8];
  if (lane == 0){ red[wv] = s; red[4 + wv] = ss; }
  __syncthreads();
  s  = red[0] + red[1] + red[2] + red[3];
  ss = red[4] + red[5] + red[6] + red[7];
  float mean = s * (1.0f / Dz);
  float var  = ss * (1.0f / Dz) - mean * mean;
  float rstd = rsqrtf(var + 1e-5f);
  float4 wg = ((const float4*)w)[tid];
  float4 bg = ((const float4*)b)[tid];
  ushort4 ov;
  ov.x = f2bf((v.x - mean) * rstd * wg.x + bg.x);
  ov.y = f2bf((v.y - mean) * rstd * wg.y + bg.y);
  ov.z = f2bf((v.z - mean) * rstd * wg.z + bg.z);
  ov.w = f2bf((v.w - mean) * rstd * wg.w + bg.w);
  *((ushort4*)(out + (long)row * Dz) + tid) = ov;
}

// ---------------- GEMM: C = A(Mx K,bf16,lda) @ Bt(NxK,bf16,ldb)^T ------------
// m97 structure: global_load_lds staging, single LDS buffer, 2 barriers/K-step.
// MODE 0: Cf fp32   1: Cf=acc+addsrc   2: Cb=bf16(gelu)   3: Cb=bf16
// TRIMAP: blockIdx.x enumerates lower-tri 128x128 tiles. TRIK: K_eff=bm+128.
template<int MODE, int BN, bool TRIMAP, bool TRIK>
__global__ __launch_bounds__(256) void k_gemm(
    const unsigned short* __restrict__ A,
    const unsigned short* __restrict__ Bt,
    float* __restrict__ Cf, unsigned short* __restrict__ Cb,
    const float* __restrict__ addsrc,
    int N, int K, int lda, int ldb,
    long sA, long sB, long sC)
{
  constexpr int BM = 128;
  constexpr int MREP = (BN == 128) ? 4 : 2;
  __shared__ unsigned short As[BM * 64];
  __shared__ unsigned short Bs[BN * 64];
  int bm, bn;
  if (TRIMAP) {
    int li = blockIdx.x;
    int r = (int)((sqrtf(8.f * li + 1.f) - 1.f) * 0.5f);
    if ((r + 1) * (r + 2) / 2 <= li) ++r;
    if (r * (r + 1) / 2 > li) --r;
    bm = r * 128; bn = (li - r * (r + 1) / 2) * 128;
  } else { bm = blockIdx.y * BM; bn = blockIdx.x * BN; }
  A  += (long)blockIdx.z * sA;
  Bt += (long)blockIdx.z * sB;
  int tid = threadIdx.x, w = tid >> 6, lane = tid & 63;
  int wr, wc;
  if (BN == 128) { wr = (w >> 1) * 64; wc = (w & 1) * 64; }
  else           { wr = w * 32;        wc = 0; }
  f4v acc[MREP][4];
  #pragma unroll
  for (int m = 0; m < MREP; ++m)
    #pragma unroll
    for (int n = 0; n < 4; ++n)
      acc[m][n] = (f4v){0.f, 0.f, 0.f, 0.f};

  int Keff = K;
  if (TRIK) Keff = min(K, bm + BM);

  int lrow = lane >> 3, lcol = (lane & 7) * 8;
  // A: 16 chunks of 8 rows; wave w stages chunks w*4..w*4+3
  const unsigned short* AgJ[4];
  unsigned short* AsJ[4];
  #pragma unroll
  for (int j = 0; j < 4; ++j) {
    AgJ[j] = A + (long)(bm + w * 32 + j * 8 + lrow) * lda + lcol;
    AsJ[j] = As + (w * 32 + j * 8) * 64;
  }
  constexpr int BCH = BN / 8 / 4;   // B chunks per wave (4 or 2)
  const unsigned short* BgJ[BCH];
  unsigned short* BsJ[BCH];
  #pragma unroll
  for (int j = 0; j < BCH; ++j) {
    BgJ[j] = Bt + (long)(bn + w * (BCH * 8) + j * 8 + lrow) * ldb + lcol;
    BsJ[j] = Bs + (w * (BCH * 8) + j * 8) * 64;
  }

  int fr = lane & 15, fg = lane >> 4;
  for (int k0 = 0; k0 < Keff; k0 += 64) {
    __syncthreads();                 // protect LDS from previous iter's readers
    #pragma unroll
    for (int j = 0; j < 4; ++j) gl16(AgJ[j] + k0, AsJ[j]);
    #pragma unroll
    for (int j = 0; j < BCH; ++j) gl16(BgJ[j] + k0, BsJ[j]);
    __syncthreads();                 // compiler drains vmcnt before barrier
    #pragma unroll
    for (int kk = 0; kk < 2; ++kk) {
      int kg = kk * 32 + fg * 8;
      s8v af[MREP], bfv[4];
      #pragma unroll
      for (int m = 0; m < MREP; ++m) af[m]  = *(const s8v*)&As[(wr + m * 16 + fr) * 64 + kg];
      #pragma unroll
      for (int n = 0; n < 4; ++n)    bfv[n] = *(const s8v*)&Bs[(wc + n * 16 + fr) * 64 + kg];
      #pragma unroll
      for (int m = 0; m < MREP; ++m)
        #pragma unroll
        for (int n = 0; n < 4; ++n)
          acc[m][n] = __builtin_amdgcn_mfma_f32_16x16x32_bf16(af[m], bfv[n], acc[m][n], 0, 0, 0);
    }
  }
  int cr0 = bm + wr + fg * 4;
  int cc0 = bn + wc + fr;
  #pragma unroll
  for (int m = 0; m < MREP; ++m)
    #pragma unroll
    for (int n = 0; n < 4; ++n)
      #pragma unroll
      for (int i = 0; i < 4; ++i) {
        long row = cr0 + m * 16 + i, col = cc0 + n * 16;
        long idx = (long)blockIdx.z * sC + row * (long)N + col;
        float v = acc[m][n][i];
        if (MODE == 1) v += addsrc[idx];
        if (MODE == 2) v = gelu_f(v);
        if (MODE <= 1) Cf[idx] = v; else Cb[idx] = f2bf(v);
      }
}

// ---------------- qkv split: RoPE + V transpose (bf16 input) -----------------
// grid: (T/32, BH). Qb/Kb: [bh][t][64] (Q scaled by 1/8). Vt: [bh][64][t].
__global__ __launch_bounds__(256) void k_qkvsplit(const unsigned short* __restrict__ qkv,
    unsigned short* __restrict__ Qb, unsigned short* __restrict__ Kb,
    unsigned short* __restrict__ Vt)
{
  __shared__ unsigned short vt_s[64][40];
  int t0 = blockIdx.x * 32;
  int bh = blockIdx.y;
  int b = bh >> 4, h = bh & 15;
  int tid = threadIdx.x;
  int tl = tid >> 3, jb = (tid & 7) * 4;
  int t = t0 + tl;
  long base = ((long)(b * Tz + t)) * 3072 + h * 64;
  float cs[4], sn[4];
  #pragma unroll
  for (int ii = 0; ii < 4; ++ii) {
    float inv = exp2f(-(float)(jb + ii) * 0.41524101186092030f);
    sincosf((float)t * inv, &sn[ii], &cs[ii]);
  }
  ushort4 q1 = *(const ushort4*)(qkv + base + jb);
  ushort4 q2 = *(const ushort4*)(qkv + base + jb + 32);
  ushort4 k1 = *(const ushort4*)(qkv + base + 1024 + jb);
  ushort4 k2 = *(const ushort4*)(qkv + base + 1024 + jb + 32);
  ushort4 v1 = *(const ushort4*)(qkv + base + 2048 + jb);
  ushort4 v2 = *(const ushort4*)(qkv + base + 2048 + jb + 32);
  float q1a[4] = {bf2f(q1.x), bf2f(q1.y), bf2f(q1.z), bf2f(q1.w)};
  float q2a[4] = {bf2f(q2.x), bf2f(q2.y), bf2f(q2.z), bf2f(q2.w)};
  float k1a[4] = {bf2f(k1.x), bf2f(k1.y), bf2f(k1.z), bf2f(k1.w)};
  float k2a[4] = {bf2f(k2.x), bf2f(k2.y), bf2f(k2.z), bf2f(k2.w)};
  unsigned short va[4] = {v1.x, v1.y, v1.z, v1.w};
  unsigned short vb[4] = {v2.x, v2.y, v2.z, v2.w};
  unsigned short qo1[4], qo2[4], ko1[4], ko2[4];
  #pragma unroll
  for (int ii = 0; ii < 4; ++ii) {
    qo1[ii] = f2bf((q1a[ii] * cs[ii] - q2a[ii] * sn[ii]) * 0.125f);
    qo2[ii] = f2bf((q1a[ii] * sn[ii] + q2a[ii] * cs[ii]) * 0.125f);
    ko1[ii] = f2bf(k1a[ii] * cs[ii] - k2a[ii] * sn[ii]);
    ko2[ii] = f2bf(k1a[ii] * sn[ii] + k2a[ii] * cs[ii]);
    vt_s[jb + ii][tl]      = va[ii];
    vt_s[jb + 32 + ii][tl] = vb[ii];
  }
  long ob = (long)bh * Tz * 64 + (long)t * 64;
  *(ushort4*)(Qb + ob + jb)      = *(ushort4*)qo1;
  *(ushort4*)(Qb + ob + jb + 32) = *(ushort4*)qo2;
  *(ushort4*)(Kb + ob + jb)      = *(ushort4*)ko1;
  *(ushort4*)(Kb + ob + jb + 32) = *(ushort4*)ko2;
  __syncthreads();
  int d = tid >> 2, tc = (tid & 3) * 8;
  *(uint4*)(Vt + (long)bh * 64 * Tz + (long)d * Tz + t0 + tc) = *(const uint4*)&vt_s[d][tc];
}

// ---------------- backbone flash attention, MFMA (hd=64) ---------------------
__global__ __launch_bounds__(256) void k_attn_mfma(
    const unsigned short* __restrict__ Qb, const unsigned short* __restrict__ Kb,
    const unsigned short* __restrict__ Vt, unsigned short* __restrict__ ao)
{
  __shared__ unsigned short Ks[64][72];
  __shared__ unsigned short Vs[64][72];   // Vs[d][key]
  __shared__ unsigned short Ps[4][16][72];
  int qb = blockIdx.x & 15;
  int bh = blockIdx.x >> 4;
  int b = bh >> 4, h = bh & 15;
  int t0 = qb * 64;
  int tid = threadIdx.x, w = tid >> 6, lane = tid & 63;
  int fr = lane & 15, fg = lane >> 4;

  const unsigned short* qp = Qb + (long)bh * Tz * 64 + (long)(t0 + w * 16 + fr) * 64 + fg * 8;
  s8v qf[2] = { *(const s8v*)qp, *(const s8v*)(qp + 32) };

  f4v o_acc[4];
  #pragma unroll
  for (int n = 0; n < 4; ++n) o_acc[n] = (f4v){0.f, 0.f, 0.f, 0.f};
  float m_[4] = {-1e30f, -1e30f, -1e30f, -1e30f};
  float l_[4] = {0.f, 0.f, 0.f, 0.f};

  int sr = tid >> 3, sc = (tid & 7) * 8;
  const unsigned short* Kg = Kb + (long)bh * Tz * 64 + (long)sr * 64 + sc;
  const unsigned short* Vg = Vt + (long)bh * 64 * Tz + (long)sr * Tz + sc;

  for (int kt = 0; kt <= qb; ++kt) {
    int k0 = kt * 64;
    __syncthreads();
    *(uint4*)&Ks[sr][sc]      = *(const uint4*)(Kg + (long)k0 * 64);
    *(uint4*)&Ks[sr + 32][sc] = *(const uint4*)(Kg + (long)(k0 + 32) * 64);
    *(uint4*)&Vs[sr][sc]      = *(const uint4*)(Vg + k0);
    *(uint4*)&Vs[sr + 32][sc] = *(const uint4*)(Vg + (long)32 * Tz + k0);
    __syncthreads();

    f4v sacc[4];
    #pragma unroll
    for (int n = 0; n < 4; ++n) sacc[n] = (f4v){0.f, 0.f, 0.f, 0.f};
    #pragma unroll
    for (int kk = 0; kk < 2; ++kk) {
      int kg = kk * 32 + fg * 8;
      #pragma unroll
      for (int n = 0; n < 4; ++n) {
        s8v bf = *(const s8v*)&Ks[n * 16 + fr][kg];
        sacc[n] = __builtin_amdgcn_mfma_f32_16x16x32_bf16(qf[kk], bf, sacc[n], 0, 0, 0);
      }
    }

    bool full = (kt < qb);
    float p[4][4], alpha[4];
    #pragma unroll
    for (int i = 0; i < 4; ++i) {
      int trow = t0 + w * 16 + fg * 4 + i;
      float mx = -1e30f;
      #pragma unroll
      for (int n = 0; n < 4; ++n) {
        float sval = sacc[n][i];
        if (!full) {
          int key = k0 + n * 16 + fr;
          sval = (key <= trow) ? sval : -1e30f;
        }
        p[n][i] = sval;
        mx = fmaxf(mx, sval);
      }
      mx = fmaxf(mx, __shfl_xor(mx, 1));
      mx = fmaxf(mx, __shfl_xor(mx, 2));
      mx = fmaxf(mx, __shfl_xor(mx, 4));
      mx = fmaxf(mx, __shfl_xor(mx, 8));
      float mnew = fmaxf(m_[i], mx);
      alpha[i] = __expf(m_[i] - mnew);
      m_[i] = mnew;
      float ps = 0.f;
      #pragma unroll
      for (int n = 0; n < 4; ++n) {
        float pv = __expf(p[n][i] - mnew);
        p[n][i] = pv;
        ps += pv;
      }
      ps += __shfl_xor(ps, 1); ps += __shfl_xor(ps, 2);
      ps += __shfl_xor(ps, 4); ps += __shfl_xor(ps, 8);
      l_[i] = l_[i] * alpha[i] + ps;
    }
    #pragma unroll
    for (int n = 0; n < 4; ++n)
      #pragma unroll
      for (int i = 0; i < 4; ++i)
        o_acc[n][i] *= alpha[i];
    #pragma unroll
    for (int n = 0; n < 4; ++n)
      #pragma unroll
      for (int i = 0; i < 4; ++i)
        Ps[w][fg * 4 + i][n * 16 + fr] = f2bf(p[n][i]);

    #pragma unroll
    for (int kk = 0; kk < 2; ++kk) {
      int kg = kk * 32 + fg * 8;
      s8v pa = *(const s8v*)&Ps[w][fr][kg];
      #pragma unroll
      for (int n = 0; n < 4; ++n) {
        s8v vb = *(const s8v*)&Vs[n * 16 + fr][kg];
        o_acc[n] = __builtin_amdgcn_mfma_f32_16x16x32_bf16(pa, vb, o_acc[n], 0, 0, 0);
      }
    }
  }

  float inv[4];
  #pragma unroll
  for (int i = 0; i < 4; ++i) inv[i] = 1.0f / l_[i];
  #pragma unroll
  for (int n = 0; n < 4; ++n)
    #pragma unroll
    for (int i = 0; i < 4; ++i) {
      int t = t0 + w * 16 + fg * 4 + i;
      ao[((long)(b * Tz + t)) * Dz + h * 64 + n * 16 + fr] = f2bf(o_acc[n][i] * inv[i]);
    }
}

// ---------------- router: softmax(h @ router_w) ------------------------------
__global__ __launch_bounds__(256) void k_router(const unsigned short* __restrict__ h,
    const float* __restrict__ rw, float* __restrict__ rout)
{
  int row = blockIdx.x, tid = threadIdx.x;
  float a0 = 0.f, a1 = 0.f, a2 = 0.f, a3 = 0.f;
  const unsigned short* hp = h + (long)row * Dz;
  for (int d = tid; d < Dz; d += 256) {
    float hv = bf2f(hp[d]);
    float4 w4 = *(const float4*)(rw + d * 4);
    a0 = fmaf(hv, w4.x, a0); a1 = fmaf(hv, w4.y, a1);
    a2 = fmaf(hv, w4.z, a2); a3 = fmaf(hv, w4.w, a3);
  }
  int lane = tid & 63, wv = tid >> 6;
  #pragma unroll
  for (int off = 32; off; off >>= 1) {
    a0 += __shfl_xor(a0, off); a1 += __shfl_xor(a1, off);
    a2 += __shfl_xor(a2, off); a3 += __shfl_xor(a3, off);
  }
  __shared__ float red[4][4];
  if (lane == 0){ red[wv][0] = a0; red[wv][1] = a1; red[wv][2] = a2; red[wv][3] = a3; }
  __syncthreads();
  if (tid == 0) {
    float s0 = red[0][0] + red[1][0] + red[2][0] + red[3][0];
    float s1 = red[0][1] + red[1][1] + red[2][1] + red[3][1];
    float s2 = red[0][2] + red[1][2] + red[2][2] + red[3][2];
    float s3 = red[0][3] + red[1][3] + red[2][3] + red[3][3];
    float mx = fmaxf(fmaxf(s0, s1), fmaxf(s2, s3));
    float e0 = __expf(s0 - mx), e1 = __expf(s1 - mx);
    float e2 = __expf(s2 - mx), e3 = __expf(s3 - mx);
    float inv = 1.0f / (e0 + e1 + e2 + e3);
    float4 r = {e0 * inv, e1 * inv, e2 * inv, e3 * inv};
    *(float4*)(rout + (long)row * 4) = r;
  }
}

// ---------------- causal softmax (attn2): S fp32 -> P bf16 -------------------
__global__ __launch_bounds__(256) void k_softmax_causal(const float* __restrict__ S,
    unsigned short* __restrict__ P, float scale)
{
  long row = blockIdx.x;
  int t = (int)(row & (Tz - 1));
  int tid = threadIdx.x;
  const float* sp = S + row * Tz;
  float4 v = *(const float4*)(sp + tid * 4);
  float vv[4];
  vv[0] = (tid*4 + 0 <= t) ? v.x * scale : -1e30f;
  vv[1] = (tid*4 + 1 <= t) ? v.y * scale : -1e30f;
  vv[2] = (tid*4 + 2 <= t) ? v.z * scale : -1e30f;
  vv[3] = (tid*4 + 3 <= t) ? v.w * scale : -1e30f;
  float mx = fmaxf(fmaxf(vv[0], vv[1]), fmaxf(vv[2], vv[3]));
  int lane = tid & 63, wv = tid >> 6;
  #pragma unroll
  for (int off = 32; off; off >>= 1) mx = fmaxf(mx, __shfl_xor(mx, off));
  __shared__ float red[8];
  if (lane == 0) red[wv] = mx;
  __syncthreads();
  mx = fmaxf(fmaxf(red[0], red[1]), fmaxf(red[2], red[3]));
  float p[4];
  float s = 0.f;
  #pragma unroll
  for (int i = 0; i < 4; ++i){ p[i] = __expf(vv[i] - mx); s += p[i]; }
  #pragma unroll
  for (int off = 32; off; off >>= 1) s += __shfl_xor(s, off);
  if (lane == 0) red[4 + wv] = s;
  __syncthreads();
  s = red[4] + red[5] + red[6] + red[7];
  float inv = 1.0f / s;
  ushort4 ov;
  ov.x = f2bf(p[0] * inv); ov.y = f2bf(p[1] * inv);
  ov.z = f2bf(p[2] * inv); ov.w = f2bf(p[3] * inv);
  *((ushort4*)(P + row * Tz) + tid) = ov;
}

// ---------------- fused conv tier + combine + sink scale ---------------------
__global__ __launch_bounds__(256) void k_combine(
    const float* __restrict__ x2, const unsigned short* __restrict__ hbf,
    const float* __restrict__ eo, const float* __restrict__ ap,
    const float* __restrict__ rout, const float* __restrict__ convw,
    const float* __restrict__ tg, const float* __restrict__ sinkp,
    float* __restrict__ outx)
{
  int row = blockIdx.x, tid = threadIdx.x;
  int t = row & (Tz - 1), b = row >> 10;
  int d0 = tid * 4;
  float4 x4 = *(const float4*)(x2 + (long)row * Dz + d0);
  float4 e4 = *(const float4*)(eo + (long)row * Dz + d0);
  float4 a4 = *(const float4*)(ap + (long)row * Dz + d0);
  float4 t4 = *(const float4*)(tg + d0);
  float4 r4 = *(const float4*)(rout + (long)row * 4);
  float sks = fabsf(sinkp[0]);
  float kv = 1.0f - r4.w * (1.0f - sks);
  const float4* cwp = (const float4*)(convw + (long)d0 * 3);
  float4 c0 = cwp[0], c1 = cwp[1], c2 = cwp[2];
  float cwf[12] = {c0.x, c0.y, c0.z, c0.w, c1.x, c1.y, c1.z, c1.w, c2.x, c2.y, c2.z, c2.w};
  float hv[3][4];
  #pragma unroll
  for (int tap = 0; tap < 3; ++tap) {
    int tt = t - 2 + tap;
    if (tt >= 0) {
      ushort4 hu = *((const ushort4*)(hbf + ((long)(b * Tz + tt)) * Dz + d0));
      hv[tap][0] = bf2f(hu.x); hv[tap][1] = bf2f(hu.y);
      hv[tap][2] = bf2f(hu.z); hv[tap][3] = bf2f(hu.w);
    } else {
      hv[tap][0] = 0.f; hv[tap][1] = 0.f; hv[tap][2] = 0.f; hv[tap][3] = 0.f;
    }
  }
  float ov[4];
  float xi[4] = {x4.x, x4.y, x4.z, x4.w};
  float ei[4] = {e4.x, e4.y, e4.z, e4.w};
  float ai[4] = {a4.x, a4.y, a4.z, a4.w};
  float ti[4] = {t4.x, t4.y, t4.z, t4.w};
  #pragma unroll
  for (int i = 0; i < 4; ++i) {
    float conv = hv[0][i] * cwf[i*3 + 0] + hv[1][i] * cwf[i*3 + 1] + hv[2][i] * cwf[i*3 + 2];
    float comb = gelu_f(conv) * r4.x + ei[i] * r4.y + ai[i] * r4.z;
    ov[i] = (xi[i] + comb * ti[i]) * kv;
  }
  float4 res = {ov[0], ov[1], ov[2], ov[3]};
  *(float4*)(outx + (long)row * Dz + d0) = res;
}

// ---------------- host launcher ----------------------------------------------
extern "C" void kernel_launch(void* const* d_in, const int* in_sizes, int n_in,
                              void* d_out, int out_size, void* d_ws, size_t ws_size,
                              hipStream_t stream) {
  (void)in_sizes; (void)n_in; (void)out_size; (void)ws_size;
  const float* x       = (const float*)d_in[0];
  const float* ln1_w   = (const float*)d_in[1];
  const float* ln1_b   = (const float*)d_in[2];
  const float* qkv_w   = (const float*)d_in[3];
  const float* out_w   = (const float*)d_in[4];
  const float* ln2_w   = (const float*)d_in[5];
  const float* ln2_b   = (const float*)d_in[6];
  const float* router_w= (const float*)d_in[7];
  const float* conv_w  = (const float*)d_in[8];
  const float* ew1     = (const float*)d_in[9];
  const float* ew2     = (const float*)d_in[10];
  const float* at_wq   = (const float*)d_in[11];
  const float* at_wk   = (const float*)d_in[12];
  const float* at_wv   = (const float*)d_in[13];
  const float* at_wo   = (const float*)d_in[14];
  const float* tg      = (const float*)d_in[15];
  const float* sinkp   = (const float*)d_in[16];
  float* outx = (float*)d_out;
  float* rout = outx + (size_t)NTz * Dz;

  char* ws = (char*)d_ws;
  size_t off = 0;
  auto alloc = [&](size_t bytes) -> char* {
    char* p = ws + off;
    off += (bytes + 255) & ~(size_t)255;
    return p;
  };
  const long TD = (long)Tz * Dz, TT = (long)Tz * Tz;

  unsigned short* w_qkvt  = (unsigned short*)alloc((size_t)3072*1024*2);
  unsigned short* w_outt  = (unsigned short*)alloc((size_t)1024*1024*2);
  unsigned short* w_ew1t  = (unsigned short*)alloc((size_t)2048*1024*2);
  unsigned short* w_ew2t  = (unsigned short*)alloc((size_t)1024*2048*2);
  unsigned short* w_qkv2t = (unsigned short*)alloc((size_t)3072*1024*2); // [wq|wk|wv]^T
  unsigned short* w_wot   = (unsigned short*)alloc((size_t)1024*1024*2);
  unsigned short* h1bf    = (unsigned short*)alloc((size_t)NTz*Dz*2);
  unsigned short* qkvb    = (unsigned short*)alloc((size_t)NTz*3072*2);  // 24 MB
  unsigned short* aobf    = (unsigned short*)alloc((size_t)NTz*Dz*2);
  float*          x2f     = (float*)alloc((size_t)NTz*Dz*4);
  unsigned short* hbf     = (unsigned short*)alloc((size_t)NTz*Dz*2);
  unsigned short* Pbf     = (unsigned short*)alloc((size_t)Bz*Tz*Tz*2);
  unsigned short* qkv2b   = (unsigned short*)alloc((size_t)NTz*3072*2);  // 24 MB
  unsigned short* v2tbf   = (unsigned short*)alloc((size_t)NTz*Dz*2);
  unsigned short* a2obf   = (unsigned short*)alloc((size_t)NTz*Dz*2);
  float*          eof_    = (float*)alloc((size_t)NTz*Dz*4);
  float*          a2pf    = (float*)alloc((size_t)NTz*Dz*4);

  // aliases (lifetime-disjoint):
  unsigned short* e1bf = qkvb;                         // dead after qkvsplit; e1 written later
  float*          Sf   = (float*)(qkvb + (size_t)8*1024*1024/2 + 4*1024*1024); // 16MB inside qkvb (offset 16MB)
  unsigned short* Qb = (unsigned short*)x2f;           // x2f written after attn
  unsigned short* Kb = Pbf;                            // Pbf written after attn
  unsigned short* Vt = (unsigned short*)a2pf;          // a2pf written after attn

  dim3 blk(256);

  // weight convert+transpose -> bf16 (N x K)
  k_convtrans<<<dim3(96, 32), blk, 0, stream>>>(qkv_w, w_qkvt, 1024, 3072);
  k_convtrans<<<dim3(32, 32), blk, 0, stream>>>(out_w, w_outt, 1024, 1024);
  k_convtrans<<<dim3(64, 32), blk, 0, stream>>>(ew1,   w_ew1t, 1024, 2048);
  k_convtrans<<<dim3(32, 64), blk, 0, stream>>>(ew2,   w_ew2t, 2048, 1024);
  k_convtrans<<<dim3(32, 32), blk, 0, stream>>>(at_wq, w_qkv2t,               1024, 1024);
  k_convtrans<<<dim3(32, 32), blk, 0, stream>>>(at_wk, w_qkv2t + 1024*1024,   1024, 1024);
  k_convtrans<<<dim3(32, 32), blk, 0, stream>>>(at_wv, w_qkv2t + 2*1024*1024, 1024, 1024);
  k_convtrans<<<dim3(32, 32), blk, 0, stream>>>(at_wo, w_wot, 1024, 1024);

  // backbone
  k_layernorm<<<NTz, blk, 0, stream>>>(x, ln1_w, ln1_b, h1bf);
  k_gemm<3,128,false,false><<<dim3(24, 32), blk, 0, stream>>>(h1bf, w_qkvt, nullptr, qkvb,
      nullptr, 3072, 1024, 1024, 1024, 0, 0, 0);
  k_qkvsplit<<<dim3(32, 64), blk, 0, stream>>>(qkvb, Qb, Kb, Vt);
  k_attn_mfma<<<dim3(1024), blk, 0, stream>>>(Qb, Kb, Vt, aobf);
  k_gemm<1,64,false,false><<<dim3(16, 32), blk, 0, stream>>>(aobf, w_outt, x2f, nullptr, x,
      1024, 1024, 1024, 1024, 0, 0, 0);
  // tiers
  k_layernorm<<<NTz, blk, 0, stream>>>(x2f, ln2_w, ln2_b, hbf);
  k_router<<<NTz, blk, 0, stream>>>(hbf, router_w, rout);
  k_gemm<2,128,false,false><<<dim3(16, 32), blk, 0, stream>>>(hbf, w_ew1t, nullptr, e1bf,
      nullptr, 2048, 1024, 1024, 1024, 0, 0, 0);
  k_gemm<0,64,false,false><<<dim3(16, 32), blk, 0, stream>>>(e1bf, w_ew2t, eof_, nullptr,
      nullptr, 1024, 2048, 2048, 2048, 0, 0, 0);
  k_gemm<3,128,false,false><<<dim3(24, 32), blk, 0, stream>>>(hbf, w_qkv2t, nullptr, qkv2b,
      nullptr, 3072, 1024, 1024, 1024, 0, 0, 0);
  k_convtrans_b<<<dim3(32, 32, 4), blk, 0, stream>>>(qkv2b + 2048, v2tbf, 3072,
      (long)Tz*3072, TD);
  k_gemm<0,128,true,false><<<dim3(36, 1, 4), blk, 0, stream>>>(qkv2b, qkv2b + 1024, Sf,
      nullptr, nullptr, 1024, 1024, 3072, 3072, (long)Tz*3072, (long)Tz*3072, TT);
  k_softmax_causal<<<NTz, blk, 0, stream>>>(Sf, Pbf, 0.03125f);
  k_gemm<3,128,false,true><<<dim3(8, 8, 4), blk, 0, stream>>>(Pbf, v2tbf, nullptr, a2obf,
      nullptr, 1024, 1024, 1024, 1024, TT, TD, TD);
  k_gemm<0,64,false,false><<<dim3(16, 32), blk, 0, stream>>>(a2obf, w_wot, a2pf, nullptr,
      nullptr, 1024, 1024, 1024, 1024, 0, 0, 0);
  k_combine<<<NTz, blk, 0, stream>>>(x2f, hbf, eof_, a2pf, rout, conv_w, tg, sinkp, outx);
}

// Round 4
// 345.979 us; speedup vs baseline: 5.9894x; 1.1967x over previous
//
#include <hip/hip_runtime.h>

#define Bz 4
#define Tz 1024
#define Dz 1024
#define Hz 16
#define NTz (Bz*Tz)

typedef short s8v __attribute__((ext_vector_type(8)));
typedef float f4v __attribute__((ext_vector_type(4)));

__device__ __forceinline__ float bf2f(unsigned short u){
  unsigned int x = ((unsigned int)u) << 16;
  return __builtin_bit_cast(float, x);
}
__device__ __forceinline__ unsigned short f2bf(float f){
  unsigned int x = __builtin_bit_cast(unsigned int, f);
  x += 0x7fffu + ((x >> 16) & 1u);
  return (unsigned short)(x >> 16);
}
// gelu tanh-approx == x * sigmoid(1.5957691216f*(x + 0.044715f*x^3))
__device__ __forceinline__ float gelu_f(float x){
  float z = 1.5957691216057308f * (x + 0.044715f * x * x * x);
  return x / (1.0f + __expf(-z));
}
// async global->LDS, 16B per lane; lds base must be wave-uniform
__device__ __forceinline__ void gl16(const unsigned short* g, unsigned short* l){
  __builtin_amdgcn_global_load_lds(
      (const __attribute__((address_space(1))) unsigned int*)g,
      (__attribute__((address_space(3))) unsigned int*)l, 16, 0, 0);
}

// ---------------- convert + transpose: fp32 (R x C) -> bf16 (C x R) ----------
__global__ __launch_bounds__(256) void k_convtrans(const float* __restrict__ in,
    unsigned short* __restrict__ out, int R, int C)
{
  __shared__ float tile[32][33];
  int c0 = blockIdx.x * 32, r0 = blockIdx.y * 32;
  int tx = threadIdx.x & 31, ty = threadIdx.x >> 5;
  #pragma unroll
  for (int i = 0; i < 32; i += 8)
    tile[ty + i][tx] = in[(long)(r0 + ty + i) * C + c0 + tx];
  __syncthreads();
  #pragma unroll
  for (int i = 0; i < 32; i += 8)
    out[(long)(c0 + ty + i) * R + r0 + tx] = f2bf(tile[tx][ty + i]);
}

// ---- bf16 strided transpose: in[r*ld + c] (1024 cols) -> out[c*1024 + r] ----
__global__ __launch_bounds__(256) void k_convtrans_b(const unsigned short* __restrict__ in,
    unsigned short* __restrict__ out, int ld, long sIn, long sOut)
{
  __shared__ unsigned short tile[32][34];
  in  += (long)blockIdx.z * sIn;
  out += (long)blockIdx.z * sOut;
  int c0 = blockIdx.x * 32, r0 = blockIdx.y * 32;
  int tx = threadIdx.x & 31, ty = threadIdx.x >> 5;
  #pragma unroll
  for (int i = 0; i < 32; i += 8)
    tile[ty + i][tx] = in[(long)(r0 + ty + i) * ld + c0 + tx];
  __syncthreads();
  #pragma unroll
  for (int i = 0; i < 32; i += 8)
    out[(long)(c0 + ty + i) * 1024 + r0 + tx] = tile[tx][ty + i];
}

// ---------------- layernorm: fp32 in -> bf16 out (row = 1024) ----------------
__global__ __launch_bounds__(256) void k_layernorm(const float* __restrict__ x,
    const float* __restrict__ w, const float* __restrict__ b,
    unsigned short* __restrict__ out)
{
  int row = blockIdx.x, tid = threadIdx.x;
  const float4* xp = (const float4*)(x + (long)row * Dz);
  float4 v = xp[tid];
  float s  = v.x + v.y + v.z + v.w;
  float ss = v.x*v.x + v.y*v.y + v.z*v.z + v.w*v.w;
  int lane = tid & 63, wv = tid >> 6;
  #pragma unroll
  for (int off = 32; off; off >>= 1){ s += __shfl_xor(s, off); ss += __shfl_xor(ss, off); }
  __shared__ float red[8];
  if (lane == 0){ red[wv] = s; red[4 + wv] = ss; }
  __syncthreads();
  s  = red[0] + red[1] + red[2] + red[3];
  ss = red[4] + red[5] + red[6] + red[7];
  float mean = s * (1.0f / Dz);
  float var  = ss * (1.0f / Dz) - mean * mean;
  float rstd = rsqrtf(var + 1e-5f);
  float4 wg = ((const float4*)w)[tid];
  float4 bg = ((const float4*)b)[tid];
  ushort4 ov;
  ov.x = f2bf((v.x - mean) * rstd * wg.x + bg.x);
  ov.y = f2bf((v.y - mean) * rstd * wg.y + bg.y);
  ov.z = f2bf((v.z - mean) * rstd * wg.z + bg.z);
  ov.w = f2bf((v.w - mean) * rstd * wg.w + bg.w);
  *((ushort4*)(out + (long)row * Dz) + tid) = ov;
}

// ---------------- GEMM: C = A(Mx K,bf16,lda) @ Bt(NxK,bf16,ldb)^T ------------
// m97 structure + T2 XOR-swizzle (pre-swizzled global source, swizzled ds_read).
// MODE 0: Cf fp32   1: Cf=acc+addsrc   2: Cb=bf16(gelu)   3: Cb=bf16
// TRIMAP: blockIdx.x enumerates lower-tri 128x128 tiles. TRIK: K_eff=bm+128.
template<int MODE, int BN, bool TRIMAP, bool TRIK>
__global__ __launch_bounds__(256) void k_gemm(
    const unsigned short* __restrict__ A,
    const unsigned short* __restrict__ Bt,
    float* __restrict__ Cf, unsigned short* __restrict__ Cb,
    const float* __restrict__ addsrc,
    int N, int K, int lda, int ldb,
    long sA, long sB, long sC)
{
  constexpr int BM = 128;
  constexpr int MREP = (BN == 128) ? 4 : 2;
  __shared__ unsigned short As[BM * 64];
  __shared__ unsigned short Bs[BN * 64];
  int bm, bn;
  if (TRIMAP) {
    int li = blockIdx.x;
    int r = (int)((sqrtf(8.f * li + 1.f) - 1.f) * 0.5f);
    if ((r + 1) * (r + 2) / 2 <= li) ++r;
    if (r * (r + 1) / 2 > li) --r;
    bm = r * 128; bn = (li - r * (r + 1) / 2) * 128;
  } else { bm = blockIdx.y * BM; bn = blockIdx.x * BN; }
  A  += (long)blockIdx.z * sA;
  Bt += (long)blockIdx.z * sB;
  int tid = threadIdx.x, w = tid >> 6, lane = tid & 63;
  int wr, wc;
  if (BN == 128) { wr = (w >> 1) * 64; wc = (w & 1) * 64; }
  else           { wr = w * 32;        wc = 0; }
  f4v acc[MREP][4];
  #pragma unroll
  for (int m = 0; m < MREP; ++m)
    #pragma unroll
    for (int n = 0; n < 4; ++n)
      acc[m][n] = (f4v){0.f, 0.f, 0.f, 0.f};

  int Keff = K;
  if (TRIK) Keff = min(K, bm + BM);

  int lrow = lane >> 3;
  // T2: inverse-swizzled global column so linear gload_lds dest lands swizzled
  int lcol = (((lane & 7) ^ lrow) * 8);
  const unsigned short* AgJ[4];
  unsigned short* AsJ[4];
  #pragma unroll
  for (int j = 0; j < 4; ++j) {
    AgJ[j] = A + (long)(bm + w * 32 + j * 8 + lrow) * lda + lcol;
    AsJ[j] = As + (w * 32 + j * 8) * 64;
  }
  constexpr int BCH = BN / 8 / 4;   // B chunks per wave (4 or 2)
  const unsigned short* BgJ[BCH];
  unsigned short* BsJ[BCH];
  #pragma unroll
  for (int j = 0; j < BCH; ++j) {
    BgJ[j] = Bt + (long)(bn + w * (BCH * 8) + j * 8 + lrow) * ldb + lcol;
    BsJ[j] = Bs + (w * (BCH * 8) + j * 8) * 64;
  }

  int fr = lane & 15, fg = lane >> 4;
  int sw = (fr & 7) * 8;            // T2 read-side XOR (row&7 == fr&7)
  for (int k0 = 0; k0 < Keff; k0 += 64) {
    __syncthreads();                 // protect LDS from previous iter's readers
    #pragma unroll
    for (int j = 0; j < 4; ++j) gl16(AgJ[j] + k0, AsJ[j]);
    #pragma unroll
    for (int j = 0; j < BCH; ++j) gl16(BgJ[j] + k0, BsJ[j]);
    __syncthreads();                 // compiler drains vmcnt before barrier
    #pragma unroll
    for (int kk = 0; kk < 2; ++kk) {
      int kg = (kk * 32 + fg * 8) ^ sw;
      s8v af[MREP], bfv[4];
      #pragma unroll
      for (int m = 0; m < MREP; ++m) af[m]  = *(const s8v*)&As[(wr + m * 16 + fr) * 64 + kg];
      #pragma unroll
      for (int n = 0; n < 4; ++n)    bfv[n] = *(const s8v*)&Bs[(wc + n * 16 + fr) * 64 + kg];
      #pragma unroll
      for (int m = 0; m < MREP; ++m)
        #pragma unroll
        for (int n = 0; n < 4; ++n)
          acc[m][n] = __builtin_amdgcn_mfma_f32_16x16x32_bf16(af[m], bfv[n], acc[m][n], 0, 0, 0);
    }
  }
  int cr0 = bm + wr + fg * 4;
  int cc0 = bn + wc + fr;
  #pragma unroll
  for (int m = 0; m < MREP; ++m)
    #pragma unroll
    for (int n = 0; n < 4; ++n)
      #pragma unroll
      for (int i = 0; i < 4; ++i) {
        long row = cr0 + m * 16 + i, col = cc0 + n * 16;
        long idx = (long)blockIdx.z * sC + row * (long)N + col;
        float v = acc[m][n][i];
        if (MODE == 1) v += addsrc[idx];
        if (MODE == 2) v = gelu_f(v);
        if (MODE <= 1) Cf[idx] = v; else Cb[idx] = f2bf(v);
      }
}

// ---------------- qkv split: RoPE + V transpose (bf16 input) -----------------
// grid: (T/32, BH). Qb/Kb: [bh][t][64] (Q scaled by 1/8). Vt: [bh][64][t].
__global__ __launch_bounds__(256) void k_qkvsplit(const unsigned short* __restrict__ qkv,
    unsigned short* __restrict__ Qb, unsigned short* __restrict__ Kb,
    unsigned short* __restrict__ Vt)
{
  __shared__ unsigned short vt_s[64][40];
  int t0 = blockIdx.x * 32;
  int bh = blockIdx.y;
  int b = bh >> 4, h = bh & 15;
  int tid = threadIdx.x;
  int tl = tid >> 3, jb = (tid & 7) * 4;
  int t = t0 + tl;
  long base = ((long)(b * Tz + t)) * 3072 + h * 64;
  float cs[4], sn[4];
  #pragma unroll
  for (int ii = 0; ii < 4; ++ii) {
    float inv = exp2f(-(float)(jb + ii) * 0.41524101186092030f);
    sincosf((float)t * inv, &sn[ii], &cs[ii]);
  }
  ushort4 q1 = *(const ushort4*)(qkv + base + jb);
  ushort4 q2 = *(const ushort4*)(qkv + base + jb + 32);
  ushort4 k1 = *(const ushort4*)(qkv + base + 1024 + jb);
  ushort4 k2 = *(const ushort4*)(qkv + base + 1024 + jb + 32);
  ushort4 v1 = *(const ushort4*)(qkv + base + 2048 + jb);
  ushort4 v2 = *(const ushort4*)(qkv + base + 2048 + jb + 32);
  float q1a[4] = {bf2f(q1.x), bf2f(q1.y), bf2f(q1.z), bf2f(q1.w)};
  float q2a[4] = {bf2f(q2.x), bf2f(q2.y), bf2f(q2.z), bf2f(q2.w)};
  float k1a[4] = {bf2f(k1.x), bf2f(k1.y), bf2f(k1.z), bf2f(k1.w)};
  float k2a[4] = {bf2f(k2.x), bf2f(k2.y), bf2f(k2.z), bf2f(k2.w)};
  unsigned short va[4] = {v1.x, v1.y, v1.z, v1.w};
  unsigned short vb[4] = {v2.x, v2.y, v2.z, v2.w};
  unsigned short qo1[4], qo2[4], ko1[4], ko2[4];
  #pragma unroll
  for (int ii = 0; ii < 4; ++ii) {
    qo1[ii] = f2bf((q1a[ii] * cs[ii] - q2a[ii] * sn[ii]) * 0.125f);
    qo2[ii] = f2bf((q1a[ii] * sn[ii] + q2a[ii] * cs[ii]) * 0.125f);
    ko1[ii] = f2bf(k1a[ii] * cs[ii] - k2a[ii] * sn[ii]);
    ko2[ii] = f2bf(k1a[ii] * sn[ii] + k2a[ii] * cs[ii]);
    vt_s[jb + ii][tl]      = va[ii];
    vt_s[jb + 32 + ii][tl] = vb[ii];
  }
  long ob = (long)bh * Tz * 64 + (long)t * 64;
  *(ushort4*)(Qb + ob + jb)      = *(ushort4*)qo1;
  *(ushort4*)(Qb + ob + jb + 32) = *(ushort4*)qo2;
  *(ushort4*)(Kb + ob + jb)      = *(ushort4*)ko1;
  *(ushort4*)(Kb + ob + jb + 32) = *(ushort4*)ko2;
  __syncthreads();
  int d = tid >> 2, tc = (tid & 3) * 8;
  *(uint4*)(Vt + (long)bh * 64 * Tz + (long)d * Tz + t0 + tc) = *(const uint4*)&vt_s[d][tc];
}

// ---------------- backbone flash attention, MFMA (hd=64) ---------------------
__global__ __launch_bounds__(256) void k_attn_mfma(
    const unsigned short* __restrict__ Qb, const unsigned short* __restrict__ Kb,
    const unsigned short* __restrict__ Vt, unsigned short* __restrict__ ao)
{
  __shared__ unsigned short Ks[64][72];
  __shared__ unsigned short Vs[64][72];   // Vs[d][key]
  __shared__ unsigned short Ps[4][16][72];
  int qb = blockIdx.x & 15;
  int bh = blockIdx.x >> 4;
  int b = bh >> 4, h = bh & 15;
  int t0 = qb * 64;
  int tid = threadIdx.x, w = tid >> 6, lane = tid & 63;
  int fr = lane & 15, fg = lane >> 4;

  const unsigned short* qp = Qb + (long)bh * Tz * 64 + (long)(t0 + w * 16 + fr) * 64 + fg * 8;
  s8v qf[2] = { *(const s8v*)qp, *(const s8v*)(qp + 32) };

  f4v o_acc[4];
  #pragma unroll
  for (int n = 0; n < 4; ++n) o_acc[n] = (f4v){0.f, 0.f, 0.f, 0.f};
  float m_[4] = {-1e30f, -1e30f, -1e30f, -1e30f};
  float l_[4] = {0.f, 0.f, 0.f, 0.f};

  int sr = tid >> 3, sc = (tid & 7) * 8;
  const unsigned short* Kg = Kb + (long)bh * Tz * 64 + (long)sr * 64 + sc;
  const unsigned short* Vg = Vt + (long)bh * 64 * Tz + (long)sr * Tz + sc;

  for (int kt = 0; kt <= qb; ++kt) {
    int k0 = kt * 64;
    __syncthreads();
    *(uint4*)&Ks[sr][sc]      = *(const uint4*)(Kg + (long)k0 * 64);
    *(uint4*)&Ks[sr + 32][sc] = *(const uint4*)(Kg + (long)(k0 + 32) * 64);
    *(uint4*)&Vs[sr][sc]      = *(const uint4*)(Vg + k0);
    *(uint4*)&Vs[sr + 32][sc] = *(const uint4*)(Vg + (long)32 * Tz + k0);
    __syncthreads();

    f4v sacc[4];
    #pragma unroll
    for (int n = 0; n < 4; ++n) sacc[n] = (f4v){0.f, 0.f, 0.f, 0.f};
    #pragma unroll
    for (int kk = 0; kk < 2; ++kk) {
      int kg = kk * 32 + fg * 8;
      #pragma unroll
      for (int n = 0; n < 4; ++n) {
        s8v bf = *(const s8v*)&Ks[n * 16 + fr][kg];
        sacc[n] = __builtin_amdgcn_mfma_f32_16x16x32_bf16(qf[kk], bf, sacc[n], 0, 0, 0);
      }
    }

    bool full = (kt < qb);
    float p[4][4], alpha[4];
    #pragma unroll
    for (int i = 0; i < 4; ++i) {
      int trow = t0 + w * 16 + fg * 4 + i;
      float mx = -1e30f;
      #pragma unroll
      for (int n = 0; n < 4; ++n) {
        float sval = sacc[n][i];
        if (!full) {
          int key = k0 + n * 16 + fr;
          sval = (key <= trow) ? sval : -1e30f;
        }
        p[n][i] = sval;
        mx = fmaxf(mx, sval);
      }
      mx = fmaxf(mx, __shfl_xor(mx, 1));
      mx = fmaxf(mx, __shfl_xor(mx, 2));
      mx = fmaxf(mx, __shfl_xor(mx, 4));
      mx = fmaxf(mx, __shfl_xor(mx, 8));
      float mnew = fmaxf(m_[i], mx);
      alpha[i] = __expf(m_[i] - mnew);
      m_[i] = mnew;
      float ps = 0.f;
      #pragma unroll
      for (int n = 0; n < 4; ++n) {
        float pv = __expf(p[n][i] - mnew);
        p[n][i] = pv;
        ps += pv;
      }
      ps += __shfl_xor(ps, 1); ps += __shfl_xor(ps, 2);
      ps += __shfl_xor(ps, 4); ps += __shfl_xor(ps, 8);
      l_[i] = l_[i] * alpha[i] + ps;
    }
    #pragma unroll
    for (int n = 0; n < 4; ++n)
      #pragma unroll
      for (int i = 0; i < 4; ++i)
        o_acc[n][i] *= alpha[i];
    #pragma unroll
    for (int n = 0; n < 4; ++n)
      #pragma unroll
      for (int i = 0; i < 4; ++i)
        Ps[w][fg * 4 + i][n * 16 + fr] = f2bf(p[n][i]);

    #pragma unroll
    for (int kk = 0; kk < 2; ++kk) {
      int kg = kk * 32 + fg * 8;
      s8v pa = *(const s8v*)&Ps[w][fr][kg];
      #pragma unroll
      for (int n = 0; n < 4; ++n) {
        s8v vb = *(const s8v*)&Vs[n * 16 + fr][kg];
        o_acc[n] = __builtin_amdgcn_mfma_f32_16x16x32_bf16(pa, vb, o_acc[n], 0, 0, 0);
      }
    }
  }

  float inv[4];
  #pragma unroll
  for (int i = 0; i < 4; ++i) inv[i] = 1.0f / l_[i];
  #pragma unroll
  for (int n = 0; n < 4; ++n)
    #pragma unroll
    for (int i = 0; i < 4; ++i) {
      int t = t0 + w * 16 + fg * 4 + i;
      ao[((long)(b * Tz + t)) * Dz + h * 64 + n * 16 + fr] = f2bf(o_acc[n][i] * inv[i]);
    }
}

// ---------------- router: softmax(h @ router_w) ------------------------------
__global__ __launch_bounds__(256) void k_router(const unsigned short* __restrict__ h,
    const float* __restrict__ rw, float* __restrict__ rout)
{
  int row = blockIdx.x, tid = threadIdx.x;
  float a0 = 0.f, a1 = 0.f, a2 = 0.f, a3 = 0.f;
  const unsigned short* hp = h + (long)row * Dz;
  for (int d = tid; d < Dz; d += 256) {
    float hv = bf2f(hp[d]);
    float4 w4 = *(const float4*)(rw + d * 4);
    a0 = fmaf(hv, w4.x, a0); a1 = fmaf(hv, w4.y, a1);
    a2 = fmaf(hv, w4.z, a2); a3 = fmaf(hv, w4.w, a3);
  }
  int lane = tid & 63, wv = tid >> 6;
  #pragma unroll
  for (int off = 32; off; off >>= 1) {
    a0 += __shfl_xor(a0, off); a1 += __shfl_xor(a1, off);
    a2 += __shfl_xor(a2, off); a3 += __shfl_xor(a3, off);
  }
  __shared__ float red[4][4];
  if (lane == 0){ red[wv][0] = a0; red[wv][1] = a1; red[wv][2] = a2; red[wv][3] = a3; }
  __syncthreads();
  if (tid == 0) {
    float s0 = red[0][0] + red[1][0] + red[2][0] + red[3][0];
    float s1 = red[0][1] + red[1][1] + red[2][1] + red[3][1];
    float s2 = red[0][2] + red[1][2] + red[2][2] + red[3][2];
    float s3 = red[0][3] + red[1][3] + red[2][3] + red[3][3];
    float mx = fmaxf(fmaxf(s0, s1), fmaxf(s2, s3));
    float e0 = __expf(s0 - mx), e1 = __expf(s1 - mx);
    float e2 = __expf(s2 - mx), e3 = __expf(s3 - mx);
    float inv = 1.0f / (e0 + e1 + e2 + e3);
    float4 r = {e0 * inv, e1 * inv, e2 * inv, e3 * inv};
    *(float4*)(rout + (long)row * 4) = r;
  }
}

// ---------------- causal softmax (attn2): S fp32 -> P bf16 -------------------
__global__ __launch_bounds__(256) void k_softmax_causal(const float* __restrict__ S,
    unsigned short* __restrict__ P, float scale)
{
  long row = blockIdx.x;
  int t = (int)(row & (Tz - 1));
  int tid = threadIdx.x;
  const float* sp = S + row * Tz;
  float4 v = *(const float4*)(sp + tid * 4);
  float vv[4];
  vv[0] = (tid*4 + 0 <= t) ? v.x * scale : -1e30f;
  vv[1] = (tid*4 + 1 <= t) ? v.y * scale : -1e30f;
  vv[2] = (tid*4 + 2 <= t) ? v.z * scale : -1e30f;
  vv[3] = (tid*4 + 3 <= t) ? v.w * scale : -1e30f;
  float mx = fmaxf(fmaxf(vv[0], vv[1]), fmaxf(vv[2], vv[3]));
  int lane = tid & 63, wv = tid >> 6;
  #pragma unroll
  for (int off = 32; off; off >>= 1) mx = fmaxf(mx, __shfl_xor(mx, off));
  __shared__ float red[8];
  if (lane == 0) red[wv] = mx;
  __syncthreads();
  mx = fmaxf(fmaxf(red[0], red[1]), fmaxf(red[2], red[3]));
  float p[4];
  float s = 0.f;
  #pragma unroll
  for (int i = 0; i < 4; ++i){ p[i] = __expf(vv[i] - mx); s += p[i]; }
  #pragma unroll
  for (int off = 32; off; off >>= 1) s += __shfl_xor(s, off);
  if (lane == 0) red[4 + wv] = s;
  __syncthreads();
  s = red[4] + red[5] + red[6] + red[7];
  float inv = 1.0f / s;
  ushort4 ov;
  ov.x = f2bf(p[0] * inv); ov.y = f2bf(p[1] * inv);
  ov.z = f2bf(p[2] * inv); ov.w = f2bf(p[3] * inv);
  *((ushort4*)(P + row * Tz) + tid) = ov;
}

// ---------------- fused conv tier + combine + sink scale ---------------------
__global__ __launch_bounds__(256) void k_combine(
    const float* __restrict__ x2, const unsigned short* __restrict__ hbf,
    const float* __restrict__ eo, const float* __restrict__ ap,
    const float* __restrict__ rout, const float* __restrict__ convw,
    const float* __restrict__ tg, const float* __restrict__ sinkp,
    float* __restrict__ outx)
{
  int row = blockIdx.x, tid = threadIdx.x;
  int t = row & (Tz - 1), b = row >> 10;
  int d0 = tid * 4;
  float4 x4 = *(const float4*)(x2 + (long)row * Dz + d0);
  float4 e4 = *(const float4*)(eo + (long)row * Dz + d0);
  float4 a4 = *(const float4*)(ap + (long)row * Dz + d0);
  float4 t4 = *(const float4*)(tg + d0);
  float4 r4 = *(const float4*)(rout + (long)row * 4);
  float sks = fabsf(sinkp[0]);
  float kv = 1.0f - r4.w * (1.0f - sks);
  const float4* cwp = (const float4*)(convw + (long)d0 * 3);
  float4 c0 = cwp[0], c1 = cwp[1], c2 = cwp[2];
  float cwf[12] = {c0.x, c0.y, c0.z, c0.w, c1.x, c1.y, c1.z, c1.w, c2.x, c2.y, c2.z, c2.w};
  float hv[3][4];
  #pragma unroll
  for (int tap = 0; tap < 3; ++tap) {
    int tt = t - 2 + tap;
    if (tt >= 0) {
      ushort4 hu = *((const ushort4*)(hbf + ((long)(b * Tz + tt)) * Dz + d0));
      hv[tap][0] = bf2f(hu.x); hv[tap][1] = bf2f(hu.y);
      hv[tap][2] = bf2f(hu.z); hv[tap][3] = bf2f(hu.w);
    } else {
      hv[tap][0] = 0.f; hv[tap][1] = 0.f; hv[tap][2] = 0.f; hv[tap][3] = 0.f;
    }
  }
  float ov[4];
  float xi[4] = {x4.x, x4.y, x4.z, x4.w};
  float ei[4] = {e4.x, e4.y, e4.z, e4.w};
  float ai[4] = {a4.x, a4.y, a4.z, a4.w};
  float ti[4] = {t4.x, t4.y, t4.z, t4.w};
  #pragma unroll
  for (int i = 0; i < 4; ++i) {
    float conv = hv[0][i] * cwf[i*3 + 0] + hv[1][i] * cwf[i*3 + 1] + hv[2][i] * cwf[i*3 + 2];
    float comb = gelu_f(conv) * r4.x + ei[i] * r4.y + ai[i] * r4.z;
    ov[i] = (xi[i] + comb * ti[i]) * kv;
  }
  float4 res = {ov[0], ov[1], ov[2], ov[3]};
  *(float4*)(outx + (long)row * Dz + d0) = res;
}

// ---------------- host launcher ----------------------------------------------
extern "C" void kernel_launch(void* const* d_in, const int* in_sizes, int n_in,
                              void* d_out, int out_size, void* d_ws, size_t ws_size,
                              hipStream_t stream) {
  (void)in_sizes; (void)n_in; (void)out_size; (void)ws_size;
  const float* x       = (const float*)d_in[0];
  const float* ln1_w   = (const float*)d_in[1];
  const float* ln1_b   = (const float*)d_in[2];
  const float* qkv_w   = (const float*)d_in[3];
  const float* out_w   = (const float*)d_in[4];
  const float* ln2_w   = (const float*)d_in[5];
  const float* ln2_b   = (const float*)d_in[6];
  const float* router_w= (const float*)d_in[7];
  const float* conv_w  = (const float*)d_in[8];
  const float* ew1     = (const float*)d_in[9];
  const float* ew2     = (const float*)d_in[10];
  const float* at_wq   = (const float*)d_in[11];
  const float* at_wk   = (const float*)d_in[12];
  const float* at_wv   = (const float*)d_in[13];
  const float* at_wo   = (const float*)d_in[14];
  const float* tg      = (const float*)d_in[15];
  const float* sinkp   = (const float*)d_in[16];
  float* outx = (float*)d_out;
  float* rout = outx + (size_t)NTz * Dz;

  char* ws = (char*)d_ws;
  size_t off = 0;
  auto alloc = [&](size_t bytes) -> char* {
    char* p = ws + off;
    off += (bytes + 255) & ~(size_t)255;
    return p;
  };
  const long TD = (long)Tz * Dz, TT = (long)Tz * Tz;

  unsigned short* w_qkvt  = (unsigned short*)alloc((size_t)3072*1024*2);
  unsigned short* w_outt  = (unsigned short*)alloc((size_t)1024*1024*2);
  unsigned short* w_ew1t  = (unsigned short*)alloc((size_t)2048*1024*2);
  unsigned short* w_ew2t  = (unsigned short*)alloc((size_t)1024*2048*2);
  unsigned short* w_qkv2t = (unsigned short*)alloc((size_t)3072*1024*2); // [wq|wk|wv]^T
  unsigned short* w_wot   = (unsigned short*)alloc((size_t)1024*1024*2);
  unsigned short* h1bf    = (unsigned short*)alloc((size_t)NTz*Dz*2);
  unsigned short* qkvb    = (unsigned short*)alloc((size_t)NTz*3072*2);  // 24 MB
  unsigned short* aobf    = (unsigned short*)alloc((size_t)NTz*Dz*2);
  float*          x2f     = (float*)alloc((size_t)NTz*Dz*4);
  unsigned short* hbf     = (unsigned short*)alloc((size_t)NTz*Dz*2);
  unsigned short* Pbf     = (unsigned short*)alloc((size_t)Bz*Tz*Tz*2);
  unsigned short* qkv2b   = (unsigned short*)alloc((size_t)NTz*3072*2);  // 24 MB
  unsigned short* v2tbf   = (unsigned short*)alloc((size_t)NTz*Dz*2);
  unsigned short* a2obf   = (unsigned short*)alloc((size_t)NTz*Dz*2);
  float*          eof_    = (float*)alloc((size_t)NTz*Dz*4);
  float*          a2pf    = (float*)alloc((size_t)NTz*Dz*4);

  // aliases (lifetime-disjoint):
  unsigned short* e1bf = qkvb;                         // dead after qkvsplit; e1 written later
  float*          Sf   = (float*)(qkvb + (size_t)8*1024*1024/2 + 4*1024*1024); // 16MB inside qkvb (offset 16MB)
  unsigned short* Qb = (unsigned short*)x2f;           // x2f written after attn
  unsigned short* Kb = Pbf;                            // Pbf written after attn
  unsigned short* Vt = (unsigned short*)a2pf;          // a2pf written after attn

  dim3 blk(256);

  // weight convert+transpose -> bf16 (N x K)
  k_convtrans<<<dim3(96, 32), blk, 0, stream>>>(qkv_w, w_qkvt, 1024, 3072);
  k_convtrans<<<dim3(32, 32), blk, 0, stream>>>(out_w, w_outt, 1024, 1024);
  k_convtrans<<<dim3(64, 32), blk, 0, stream>>>(ew1,   w_ew1t, 1024, 2048);
  k_convtrans<<<dim3(32, 64), blk, 0, stream>>>(ew2,   w_ew2t, 2048, 1024);
  k_convtrans<<<dim3(32, 32), blk, 0, stream>>>(at_wq, w_qkv2t,               1024, 1024);
  k_convtrans<<<dim3(32, 32), blk, 0, stream>>>(at_wk, w_qkv2t + 1024*1024,   1024, 1024);
  k_convtrans<<<dim3(32, 32), blk, 0, stream>>>(at_wv, w_qkv2t + 2*1024*1024, 1024, 1024);
  k_convtrans<<<dim3(32, 32), blk, 0, stream>>>(at_wo, w_wot, 1024, 1024);

  // backbone
  k_layernorm<<<NTz, blk, 0, stream>>>(x, ln1_w, ln1_b, h1bf);
  k_gemm<3,128,false,false><<<dim3(24, 32), blk, 0, stream>>>(h1bf, w_qkvt, nullptr, qkvb,
      nullptr, 3072, 1024, 1024, 1024, 0, 0, 0);
  k_qkvsplit<<<dim3(32, 64), blk, 0, stream>>>(qkvb, Qb, Kb, Vt);
  k_attn_mfma<<<dim3(1024), blk, 0, stream>>>(Qb, Kb, Vt, aobf);
  k_gemm<1,64,false,false><<<dim3(16, 32), blk, 0, stream>>>(aobf, w_outt, x2f, nullptr, x,
      1024, 1024, 1024, 1024, 0, 0, 0);
  // tiers
  k_layernorm<<<NTz, blk, 0, stream>>>(x2f, ln2_w, ln2_b, hbf);
  k_router<<<NTz, blk, 0, stream>>>(hbf, router_w, rout);
  k_gemm<2,128,false,false><<<dim3(16, 32), blk, 0, stream>>>(hbf, w_ew1t, nullptr, e1bf,
      nullptr, 2048, 1024, 1024, 1024, 0, 0, 0);
  k_gemm<0,64,false,false><<<dim3(16, 32), blk, 0, stream>>>(e1bf, w_ew2t, eof_, nullptr,
      nullptr, 1024, 2048, 2048, 2048, 0, 0, 0);
  k_gemm<3,128,false,false><<<dim3(24, 32), blk, 0, stream>>>(hbf, w_qkv2t, nullptr, qkv2b,
      nullptr, 3072, 1024, 1024, 1024, 0, 0, 0);
  k_convtrans_b<<<dim3(32, 32, 4), blk, 0, stream>>>(qkv2b + 2048, v2tbf, 3072,
      (long)Tz*3072, TD);
  k_gemm<0,128,true,false><<<dim3(36, 1, 4), blk, 0, stream>>>(qkv2b, qkv2b + 1024, Sf,
      nullptr, nullptr, 1024, 1024, 3072, 3072, (long)Tz*3072, (long)Tz*3072, TT);
  k_softmax_causal<<<NTz, blk, 0, stream>>>(Sf, Pbf, 0.03125f);
  k_gemm<3,128,false,true><<<dim3(8, 8, 4), blk, 0, stream>>>(Pbf, v2tbf, nullptr, a2obf,
      nullptr, 1024, 1024, 1024, 1024, TT, TD, TD);
  k_gemm<0,64,false,false><<<dim3(16, 32), blk, 0, stream>>>(a2obf, w_wot, a2pf, nullptr,
      nullptr, 1024, 1024, 1024, 1024, 0, 0, 0);
  k_combine<<<NTz, blk, 0, stream>>>(x2f, hbf, eof_, a2pf, rout, conv_w, tg, sinkp, outx);
}

// Round 5
// 308.892 us; speedup vs baseline: 6.7085x; 1.1201x over previous
//
#include <hip/hip_runtime.h>

#define Bz 4
#define Tz 1024
#define Dz 1024
#define Hz 16
#define NTz (Bz*Tz)

typedef short s8v __attribute__((ext_vector_type(8)));
typedef float f4v __attribute__((ext_vector_type(4)));

__device__ __forceinline__ float bf2f(unsigned short u){
  unsigned int x = ((unsigned int)u) << 16;
  return __builtin_bit_cast(float, x);
}
__device__ __forceinline__ unsigned short f2bf(float f){
  unsigned int x = __builtin_bit_cast(unsigned int, f);
  x += 0x7fffu + ((x >> 16) & 1u);
  return (unsigned short)(x >> 16);
}
// gelu tanh-approx == x * sigmoid(1.5957691216f*(x + 0.044715f*x^3))
__device__ __forceinline__ float gelu_f(float x){
  float z = 1.5957691216057308f * (x + 0.044715f * x * x * x);
  return x / (1.0f + __expf(-z));
}
// async global->LDS, 16B per lane; lds base must be wave-uniform
__device__ __forceinline__ void gl16(const unsigned short* g, unsigned short* l){
  __builtin_amdgcn_global_load_lds(
      (const __attribute__((address_space(1))) unsigned int*)g,
      (__attribute__((address_space(3))) unsigned int*)l, 16, 0, 0);
}

// ---------------- convert + transpose: fp32 (R x C) -> bf16 (C x R) ----------
__global__ __launch_bounds__(256) void k_convtrans(const float* __restrict__ in,
    unsigned short* __restrict__ out, int R, int C)
{
  __shared__ float tile[32][33];
  int c0 = blockIdx.x * 32, r0 = blockIdx.y * 32;
  int tx = threadIdx.x & 31, ty = threadIdx.x >> 5;
  #pragma unroll
  for (int i = 0; i < 32; i += 8)
    tile[ty + i][tx] = in[(long)(r0 + ty + i) * C + c0 + tx];
  __syncthreads();
  #pragma unroll
  for (int i = 0; i < 32; i += 8)
    out[(long)(c0 + ty + i) * R + r0 + tx] = f2bf(tile[tx][ty + i]);
}

// ---- bf16 strided transpose: in[r*ld + c] (1024 cols) -> out[c*1024 + r] ----
__global__ __launch_bounds__(256) void k_convtrans_b(const unsigned short* __restrict__ in,
    unsigned short* __restrict__ out, int ld, long sIn, long sOut)
{
  __shared__ unsigned short tile[32][34];
  in  += (long)blockIdx.z * sIn;
  out += (long)blockIdx.z * sOut;
  int c0 = blockIdx.x * 32, r0 = blockIdx.y * 32;
  int tx = threadIdx.x & 31, ty = threadIdx.x >> 5;
  #pragma unroll
  for (int i = 0; i < 32; i += 8)
    tile[ty + i][tx] = in[(long)(r0 + ty + i) * ld + c0 + tx];
  __syncthreads();
  #pragma unroll
  for (int i = 0; i < 32; i += 8)
    out[(long)(c0 + ty + i) * 1024 + r0 + tx] = tile[tx][ty + i];
}

// ---------------- layernorm: fp32 in -> bf16 out (row = 1024) ----------------
__global__ __launch_bounds__(256) void k_layernorm(const float* __restrict__ x,
    const float* __restrict__ w, const float* __restrict__ b,
    unsigned short* __restrict__ out)
{
  int row = blockIdx.x, tid = threadIdx.x;
  const float4* xp = (const float4*)(x + (long)row * Dz);
  float4 v = xp[tid];
  float s  = v.x + v.y + v.z + v.w;
  float ss = v.x*v.x + v.y*v.y + v.z*v.z + v.w*v.w;
  int lane = tid & 63, wv = tid >> 6;
  #pragma unroll
  for (int off = 32; off; off >>= 1){ s += __shfl_xor(s, off); ss += __shfl_xor(ss, off); }
  __shared__ float red[8];
  if (lane == 0){ red[wv] = s; red[4 + wv] = ss; }
  __syncthreads();
  s  = red[0] + red[1] + red[2] + red[3];
  ss = red[4] + red[5] + red[6] + red[7];
  float mean = s * (1.0f / Dz);
  float var  = ss * (1.0f / Dz) - mean * mean;
  float rstd = rsqrtf(var + 1e-5f);
  float4 wg = ((const float4*)w)[tid];
  float4 bg = ((const float4*)b)[tid];
  ushort4 ov;
  ov.x = f2bf((v.x - mean) * rstd * wg.x + bg.x);
  ov.y = f2bf((v.y - mean) * rstd * wg.y + bg.y);
  ov.z = f2bf((v.z - mean) * rstd * wg.z + bg.z);
  ov.w = f2bf((v.w - mean) * rstd * wg.w + bg.w);
  *((ushort4*)(out + (long)row * Dz) + tid) = ov;
}

// ---------------- GEMM: C = A(MxK,bf16,lda) @ Bt(NxK,bf16,ldb)^T -------------
// m97 structure + T2 XOR-swizzle. DBUF: 2-phase pipeline (stage next tile
// before compute, one barrier/iter). MODE 0: fp32  1: fp32+addsrc
// 2: bf16(gelu)  3: bf16.  TRIMAP (BN=64): lower-tri tiles c<=2r+1.
// TRIK: Keff=bm+128.
template<int MODE, int BN, bool TRIMAP, bool TRIK, bool DBUF>
__global__ __launch_bounds__(256) void k_gemm(
    const unsigned short* __restrict__ A,
    const unsigned short* __restrict__ Bt,
    float* __restrict__ Cf, unsigned short* __restrict__ Cb,
    const float* __restrict__ addsrc,
    int N, int K, int lda, int ldb,
    long sA, long sB, long sC)
{
  constexpr int BM = 128;
  constexpr int MREP = (BN == 128) ? 4 : 2;
  constexpr int NB = DBUF ? 2 : 1;
  __shared__ unsigned short As[NB][BM * 64];
  __shared__ unsigned short Bs[NB][BN * 64];
  int bm, bn;
  if (TRIMAP) {
    // BN=64: tiles (r,c) with c <= 2r+1; cum(r) = r*(r+1)
    int li = blockIdx.x;
    int r = (int)((sqrtf(4.f * li + 1.f) - 1.f) * 0.5f);
    if ((r + 1) * (r + 2) <= li) ++r;
    if (r * (r + 1) > li) --r;
    bm = r * 128; bn = (li - r * (r + 1)) * BN;
  } else { bm = blockIdx.y * BM; bn = blockIdx.x * BN; }
  A  += (long)blockIdx.z * sA;
  Bt += (long)blockIdx.z * sB;
  int tid = threadIdx.x, w = tid >> 6, lane = tid & 63;
  int wr, wc;
  if (BN == 128) { wr = (w >> 1) * 64; wc = (w & 1) * 64; }
  else           { wr = w * 32;        wc = 0; }
  f4v acc[MREP][4];
  #pragma unroll
  for (int m = 0; m < MREP; ++m)
    #pragma unroll
    for (int n = 0; n < 4; ++n)
      acc[m][n] = (f4v){0.f, 0.f, 0.f, 0.f};

  int Keff = K;
  if (TRIK) Keff = min(K, bm + BM);

  int lrow = lane >> 3;
  // T2: inverse-swizzled global column so linear gload_lds dest lands swizzled
  int lcol = (((lane & 7) ^ lrow) * 8);
  const unsigned short* AgJ[4];
  int AsOff[4];
  #pragma unroll
  for (int j = 0; j < 4; ++j) {
    AgJ[j] = A + (long)(bm + w * 32 + j * 8 + lrow) * lda + lcol;
    AsOff[j] = (w * 32 + j * 8) * 64;
  }
  constexpr int BCH = BN / 8 / 4;   // B chunks per wave (4 or 2)
  const unsigned short* BgJ[BCH];
  int BsOff[BCH];
  #pragma unroll
  for (int j = 0; j < BCH; ++j) {
    BgJ[j] = Bt + (long)(bn + w * (BCH * 8) + j * 8 + lrow) * ldb + lcol;
    BsOff[j] = (w * (BCH * 8) + j * 8) * 64;
  }

  int fr = lane & 15, fg = lane >> 4;
  int sw = (fr & 7) * 8;            // T2 read-side XOR (row&7 == fr&7)

  auto stage = [&](int buf, int k0){
    #pragma unroll
    for (int j = 0; j < 4; ++j) gl16(AgJ[j] + k0, &As[buf][AsOff[j]]);
    #pragma unroll
    for (int j = 0; j < BCH; ++j) gl16(BgJ[j] + k0, &Bs[buf][BsOff[j]]);
  };
  auto compute = [&](int buf){
    #pragma unroll
    for (int kk = 0; kk < 2; ++kk) {
      int kg = (kk * 32 + fg * 8) ^ sw;
      s8v af[MREP], bfv[4];
      #pragma unroll
      for (int m = 0; m < MREP; ++m) af[m]  = *(const s8v*)&As[buf][(wr + m * 16 + fr) * 64 + kg];
      #pragma unroll
      for (int n = 0; n < 4; ++n)    bfv[n] = *(const s8v*)&Bs[buf][(wc + n * 16 + fr) * 64 + kg];
      #pragma unroll
      for (int m = 0; m < MREP; ++m)
        #pragma unroll
        for (int n = 0; n < 4; ++n)
          acc[m][n] = __builtin_amdgcn_mfma_f32_16x16x32_bf16(af[m], bfv[n], acc[m][n], 0, 0, 0);
    }
  };

  if (DBUF) {
    int cur = 0;
    stage(0, 0);
    __syncthreads();
    for (int k0 = 0; k0 < Keff; k0 += 64) {
      if (k0 + 64 < Keff) stage(cur ^ 1, k0 + 64);
      compute(cur);
      __syncthreads();
      cur ^= 1;
    }
  } else {
    for (int k0 = 0; k0 < Keff; k0 += 64) {
      __syncthreads();
      stage(0, k0);
      __syncthreads();
      compute(0);
    }
  }

  int cr0 = bm + wr + fg * 4;
  int cc0 = bn + wc + fr;
  #pragma unroll
  for (int m = 0; m < MREP; ++m)
    #pragma unroll
    for (int n = 0; n < 4; ++n)
      #pragma unroll
      for (int i = 0; i < 4; ++i) {
        long row = cr0 + m * 16 + i, col = cc0 + n * 16;
        long idx = (long)blockIdx.z * sC + row * (long)N + col;
        float v = acc[m][n][i];
        if (MODE == 1) v += addsrc[idx];
        if (MODE == 2) v = gelu_f(v);
        if (MODE <= 1) Cf[idx] = v; else Cb[idx] = f2bf(v);
      }
}

// ---------------- qkv split: RoPE + V transpose (bf16 input) -----------------
// grid: (T/32, BH). Qb/Kb: [bh][t][64] (Q scaled by 1/8). Vt: [bh][64][t].
__global__ __launch_bounds__(256) void k_qkvsplit(const unsigned short* __restrict__ qkv,
    unsigned short* __restrict__ Qb, unsigned short* __restrict__ Kb,
    unsigned short* __restrict__ Vt)
{
  __shared__ unsigned short vt_s[64][40];
  int t0 = blockIdx.x * 32;
  int bh = blockIdx.y;
  int b = bh >> 4, h = bh & 15;
  int tid = threadIdx.x;
  int tl = tid >> 3, jb = (tid & 7) * 4;
  int t = t0 + tl;
  long base = ((long)(b * Tz + t)) * 3072 + h * 64;
  float cs[4], sn[4];
  #pragma unroll
  for (int ii = 0; ii < 4; ++ii) {
    float inv = exp2f(-(float)(jb + ii) * 0.41524101186092030f);
    sincosf((float)t * inv, &sn[ii], &cs[ii]);
  }
  ushort4 q1 = *(const ushort4*)(qkv + base + jb);
  ushort4 q2 = *(const ushort4*)(qkv + base + jb + 32);
  ushort4 k1 = *(const ushort4*)(qkv + base + 1024 + jb);
  ushort4 k2 = *(const ushort4*)(qkv + base + 1024 + jb + 32);
  ushort4 v1 = *(const ushort4*)(qkv + base + 2048 + jb);
  ushort4 v2 = *(const ushort4*)(qkv + base + 2048 + jb + 32);
  float q1a[4] = {bf2f(q1.x), bf2f(q1.y), bf2f(q1.z), bf2f(q1.w)};
  float q2a[4] = {bf2f(q2.x), bf2f(q2.y), bf2f(q2.z), bf2f(q2.w)};
  float k1a[4] = {bf2f(k1.x), bf2f(k1.y), bf2f(k1.z), bf2f(k1.w)};
  float k2a[4] = {bf2f(k2.x), bf2f(k2.y), bf2f(k2.z), bf2f(k2.w)};
  unsigned short va[4] = {v1.x, v1.y, v1.z, v1.w};
  unsigned short vb[4] = {v2.x, v2.y, v2.z, v2.w};
  unsigned short qo1[4], qo2[4], ko1[4], ko2[4];
  #pragma unroll
  for (int ii = 0; ii < 4; ++ii) {
    qo1[ii] = f2bf((q1a[ii] * cs[ii] - q2a[ii] * sn[ii]) * 0.125f);
    qo2[ii] = f2bf((q1a[ii] * sn[ii] + q2a[ii] * cs[ii]) * 0.125f);
    ko1[ii] = f2bf(k1a[ii] * cs[ii] - k2a[ii] * sn[ii]);
    ko2[ii] = f2bf(k1a[ii] * sn[ii] + k2a[ii] * cs[ii]);
    vt_s[jb + ii][tl]      = va[ii];
    vt_s[jb + 32 + ii][tl] = vb[ii];
  }
  long ob = (long)bh * Tz * 64 + (long)t * 64;
  *(ushort4*)(Qb + ob + jb)      = *(ushort4*)qo1;
  *(ushort4*)(Qb + ob + jb + 32) = *(ushort4*)qo2;
  *(ushort4*)(Kb + ob + jb)      = *(ushort4*)ko1;
  *(ushort4*)(Kb + ob + jb + 32) = *(ushort4*)ko2;
  __syncthreads();
  int d = tid >> 2, tc = (tid & 3) * 8;
  *(uint4*)(Vt + (long)bh * 64 * Tz + (long)d * Tz + t0 + tc) = *(const uint4*)&vt_s[d][tc];
}

// ---------------- backbone flash attention, MFMA (hd=64) ---------------------
// heavy-first dispatch: qb = 15 - bid>>6 so long blocks start first.
__global__ __launch_bounds__(256) void k_attn_mfma(
    const unsigned short* __restrict__ Qb, const unsigned short* __restrict__ Kb,
    const unsigned short* __restrict__ Vt, unsigned short* __restrict__ ao)
{
  __shared__ unsigned short Ks[64][72];
  __shared__ unsigned short Vs[64][72];   // Vs[d][key]
  __shared__ unsigned short Ps[4][16][72];
  int qb = 15 - (blockIdx.x >> 6);
  int bh = blockIdx.x & 63;
  int b = bh >> 4, h = bh & 15;
  int t0 = qb * 64;
  int tid = threadIdx.x, w = tid >> 6, lane = tid & 63;
  int fr = lane & 15, fg = lane >> 4;

  const unsigned short* qp = Qb + (long)bh * Tz * 64 + (long)(t0 + w * 16 + fr) * 64 + fg * 8;
  s8v qf[2] = { *(const s8v*)qp, *(const s8v*)(qp + 32) };

  f4v o_acc[4];
  #pragma unroll
  for (int n = 0; n < 4; ++n) o_acc[n] = (f4v){0.f, 0.f, 0.f, 0.f};
  float m_[4] = {-1e30f, -1e30f, -1e30f, -1e30f};
  float l_[4] = {0.f, 0.f, 0.f, 0.f};

  int sr = tid >> 3, sc = (tid & 7) * 8;
  const unsigned short* Kg = Kb + (long)bh * Tz * 64 + (long)sr * 64 + sc;
  const unsigned short* Vg = Vt + (long)bh * 64 * Tz + (long)sr * Tz + sc;

  for (int kt = 0; kt <= qb; ++kt) {
    int k0 = kt * 64;
    __syncthreads();
    *(uint4*)&Ks[sr][sc]      = *(const uint4*)(Kg + (long)k0 * 64);
    *(uint4*)&Ks[sr + 32][sc] = *(const uint4*)(Kg + (long)(k0 + 32) * 64);
    *(uint4*)&Vs[sr][sc]      = *(const uint4*)(Vg + k0);
    *(uint4*)&Vs[sr + 32][sc] = *(const uint4*)(Vg + (long)32 * Tz + k0);
    __syncthreads();

    f4v sacc[4];
    #pragma unroll
    for (int n = 0; n < 4; ++n) sacc[n] = (f4v){0.f, 0.f, 0.f, 0.f};
    #pragma unroll
    for (int kk = 0; kk < 2; ++kk) {
      int kg = kk * 32 + fg * 8;
      #pragma unroll
      for (int n = 0; n < 4; ++n) {
        s8v bf = *(const s8v*)&Ks[n * 16 + fr][kg];
        sacc[n] = __builtin_amdgcn_mfma_f32_16x16x32_bf16(qf[kk], bf, sacc[n], 0, 0, 0);
      }
    }

    bool full = (kt < qb);
    float p[4][4], alpha[4];
    #pragma unroll
    for (int i = 0; i < 4; ++i) {
      int trow = t0 + w * 16 + fg * 4 + i;
      float mx = -1e30f;
      #pragma unroll
      for (int n = 0; n < 4; ++n) {
        float sval = sacc[n][i];
        if (!full) {
          int key = k0 + n * 16 + fr;
          sval = (key <= trow) ? sval : -1e30f;
        }
        p[n][i] = sval;
        mx = fmaxf(mx, sval);
      }
      mx = fmaxf(mx, __shfl_xor(mx, 1));
      mx = fmaxf(mx, __shfl_xor(mx, 2));
      mx = fmaxf(mx, __shfl_xor(mx, 4));
      mx = fmaxf(mx, __shfl_xor(mx, 8));
      float mnew = fmaxf(m_[i], mx);
      alpha[i] = __expf(m_[i] - mnew);
      m_[i] = mnew;
      float ps = 0.f;
      #pragma unroll
      for (int n = 0; n < 4; ++n) {
        float pv = __expf(p[n][i] - mnew);
        p[n][i] = pv;
        ps += pv;
      }
      ps += __shfl_xor(ps, 1); ps += __shfl_xor(ps, 2);
      ps += __shfl_xor(ps, 4); ps += __shfl_xor(ps, 8);
      l_[i] = l_[i] * alpha[i] + ps;
    }
    #pragma unroll
    for (int n = 0; n < 4; ++n)
      #pragma unroll
      for (int i = 0; i < 4; ++i)
        o_acc[n][i] *= alpha[i];
    #pragma unroll
    for (int n = 0; n < 4; ++n)
      #pragma unroll
      for (int i = 0; i < 4; ++i)
        Ps[w][fg * 4 + i][n * 16 + fr] = f2bf(p[n][i]);

    #pragma unroll
    for (int kk = 0; kk < 2; ++kk) {
      int kg = kk * 32 + fg * 8;
      s8v pa = *(const s8v*)&Ps[w][fr][kg];
      #pragma unroll
      for (int n = 0; n < 4; ++n) {
        s8v vb = *(const s8v*)&Vs[n * 16 + fr][kg];
        o_acc[n] = __builtin_amdgcn_mfma_f32_16x16x32_bf16(pa, vb, o_acc[n], 0, 0, 0);
      }
    }
  }

  float inv[4];
  #pragma unroll
  for (int i = 0; i < 4; ++i) inv[i] = 1.0f / l_[i];
  #pragma unroll
  for (int n = 0; n < 4; ++n)
    #pragma unroll
    for (int i = 0; i < 4; ++i) {
      int t = t0 + w * 16 + fg * 4 + i;
      ao[((long)(b * Tz + t)) * Dz + h * 64 + n * 16 + fr] = f2bf(o_acc[n][i] * inv[i]);
    }
}

// ---------------- router: softmax(h @ router_w) ------------------------------
__global__ __launch_bounds__(256) void k_router(const unsigned short* __restrict__ h,
    const float* __restrict__ rw, float* __restrict__ rout)
{
  int row = blockIdx.x, tid = threadIdx.x;
  float a0 = 0.f, a1 = 0.f, a2 = 0.f, a3 = 0.f;
  const unsigned short* hp = h + (long)row * Dz;
  for (int d = tid; d < Dz; d += 256) {
    float hv = bf2f(hp[d]);
    float4 w4 = *(const float4*)(rw + d * 4);
    a0 = fmaf(hv, w4.x, a0); a1 = fmaf(hv, w4.y, a1);
    a2 = fmaf(hv, w4.z, a2); a3 = fmaf(hv, w4.w, a3);
  }
  int lane = tid & 63, wv = tid >> 6;
  #pragma unroll
  for (int off = 32; off; off >>= 1) {
    a0 += __shfl_xor(a0, off); a1 += __shfl_xor(a1, off);
    a2 += __shfl_xor(a2, off); a3 += __shfl_xor(a3, off);
  }
  __shared__ float red[4][4];
  if (lane == 0){ red[wv][0] = a0; red[wv][1] = a1; red[wv][2] = a2; red[wv][3] = a3; }
  __syncthreads();
  if (tid == 0) {
    float s0 = red[0][0] + red[1][0] + red[2][0] + red[3][0];
    float s1 = red[0][1] + red[1][1] + red[2][1] + red[3][1];
    float s2 = red[0][2] + red[1][2] + red[2][2] + red[3][2];
    float s3 = red[0][3] + red[1][3] + red[2][3] + red[3][3];
    float mx = fmaxf(fmaxf(s0, s1), fmaxf(s2, s3));
    float e0 = __expf(s0 - mx), e1 = __expf(s1 - mx);
    float e2 = __expf(s2 - mx), e3 = __expf(s3 - mx);
    float inv = 1.0f / (e0 + e1 + e2 + e3);
    float4 r = {e0 * inv, e1 * inv, e2 * inv, e3 * inv};
    *(float4*)(rout + (long)row * 4) = r;
  }
}

// ---------------- causal softmax (attn2): S fp32 -> P bf16 -------------------
__global__ __launch_bounds__(256) void k_softmax_causal(const float* __restrict__ S,
    unsigned short* __restrict__ P, float scale)
{
  long row = blockIdx.x;
  int t = (int)(row & (Tz - 1));
  int tid = threadIdx.x;
  const float* sp = S + row * Tz;
  float4 v = *(const float4*)(sp + tid * 4);
  float vv[4];
  vv[0] = (tid*4 + 0 <= t) ? v.x * scale : -1e30f;
  vv[1] = (tid*4 + 1 <= t) ? v.y * scale : -1e30f;
  vv[2] = (tid*4 + 2 <= t) ? v.z * scale : -1e30f;
  vv[3] = (tid*4 + 3 <= t) ? v.w * scale : -1e30f;
  float mx = fmaxf(fmaxf(vv[0], vv[1]), fmaxf(vv[2], vv[3]));
  int lane = tid & 63, wv = tid >> 6;
  #pragma unroll
  for (int off = 32; off; off >>= 1) mx = fmaxf(mx, __shfl_xor(mx, off));
  __shared__ float red[8];
  if (lane == 0) red[wv] = mx;
  __syncthreads();
  mx = fmaxf(fmaxf(red[0], red[1]), fmaxf(red[2], red[3]));
  float p[4];
  float s = 0.f;
  #pragma unroll
  for (int i = 0; i < 4; ++i){ p[i] = __expf(vv[i] - mx); s += p[i]; }
  #pragma unroll
  for (int off = 32; off; off >>= 1) s += __shfl_xor(s, off);
  if (lane == 0) red[4 + wv] = s;
  __syncthreads();
  s = red[4] + red[5] + red[6] + red[7];
  float inv = 1.0f / s;
  ushort4 ov;
  ov.x = f2bf(p[0] * inv); ov.y = f2bf(p[1] * inv);
  ov.z = f2bf(p[2] * inv); ov.w = f2bf(p[3] * inv);
  *((ushort4*)(P + row * Tz) + tid) = ov;
}

// ---------------- fused conv tier + combine + sink scale ---------------------
__global__ __launch_bounds__(256) void k_combine(
    const float* __restrict__ x2, const unsigned short* __restrict__ hbf,
    const float* __restrict__ eo, const float* __restrict__ ap,
    const float* __restrict__ rout, const float* __restrict__ convw,
    const float* __restrict__ tg, const float* __restrict__ sinkp,
    float* __restrict__ outx)
{
  int row = blockIdx.x, tid = threadIdx.x;
  int t = row & (Tz - 1), b = row >> 10;
  int d0 = tid * 4;
  float4 x4 = *(const float4*)(x2 + (long)row * Dz + d0);
  float4 e4 = *(const float4*)(eo + (long)row * Dz + d0);
  float4 a4 = *(const float4*)(ap + (long)row * Dz + d0);
  float4 t4 = *(const float4*)(tg + d0);
  float4 r4 = *(const float4*)(rout + (long)row * 4);
  float sks = fabsf(sinkp[0]);
  float kv = 1.0f - r4.w * (1.0f - sks);
  const float4* cwp = (const float4*)(convw + (long)d0 * 3);
  float4 c0 = cwp[0], c1 = cwp[1], c2 = cwp[2];
  float cwf[12] = {c0.x, c0.y, c0.z, c0.w, c1.x, c1.y, c1.z, c1.w, c2.x, c2.y, c2.z, c2.w};
  float hv[3][4];
  #pragma unroll
  for (int tap = 0; tap < 3; ++tap) {
    int tt = t - 2 + tap;
    if (tt >= 0) {
      ushort4 hu = *((const ushort4*)(hbf + ((long)(b * Tz + tt)) * Dz + d0));
      hv[tap][0] = bf2f(hu.x); hv[tap][1] = bf2f(hu.y);
      hv[tap][2] = bf2f(hu.z); hv[tap][3] = bf2f(hu.w);
    } else {
      hv[tap][0] = 0.f; hv[tap][1] = 0.f; hv[tap][2] = 0.f; hv[tap][3] = 0.f;
    }
  }
  float ov[4];
  float xi[4] = {x4.x, x4.y, x4.z, x4.w};
  float ei[4] = {e4.x, e4.y, e4.z, e4.w};
  float ai[4] = {a4.x, a4.y, a4.z, a4.w};
  float ti[4] = {t4.x, t4.y, t4.z, t4.w};
  #pragma unroll
  for (int i = 0; i < 4; ++i) {
    float conv = hv[0][i] * cwf[i*3 + 0] + hv[1][i] * cwf[i*3 + 1] + hv[2][i] * cwf[i*3 + 2];
    float comb = gelu_f(conv) * r4.x + ei[i] * r4.y + ai[i] * r4.z;
    ov[i] = (xi[i] + comb * ti[i]) * kv;
  }
  float4 res = {ov[0], ov[1], ov[2], ov[3]};
  *(float4*)(outx + (long)row * Dz + d0) = res;
}

// ---------------- host launcher ----------------------------------------------
extern "C" void kernel_launch(void* const* d_in, const int* in_sizes, int n_in,
                              void* d_out, int out_size, void* d_ws, size_t ws_size,
                              hipStream_t stream) {
  (void)in_sizes; (void)n_in; (void)out_size; (void)ws_size;
  const float* x       = (const float*)d_in[0];
  const float* ln1_w   = (const float*)d_in[1];
  const float* ln1_b   = (const float*)d_in[2];
  const float* qkv_w   = (const float*)d_in[3];
  const float* out_w   = (const float*)d_in[4];
  const float* ln2_w   = (const float*)d_in[5];
  const float* ln2_b   = (const float*)d_in[6];
  const float* router_w= (const float*)d_in[7];
  const float* conv_w  = (const float*)d_in[8];
  const float* ew1     = (const float*)d_in[9];
  const float* ew2     = (const float*)d_in[10];
  const float* at_wq   = (const float*)d_in[11];
  const float* at_wk   = (const float*)d_in[12];
  const float* at_wv   = (const float*)d_in[13];
  const float* at_wo   = (const float*)d_in[14];
  const float* tg      = (const float*)d_in[15];
  const float* sinkp   = (const float*)d_in[16];
  float* outx = (float*)d_out;
  float* rout = outx + (size_t)NTz * Dz;

  char* ws = (char*)d_ws;
  size_t off = 0;
  auto alloc = [&](size_t bytes) -> char* {
    char* p = ws + off;
    off += (bytes + 255) & ~(size_t)255;
    return p;
  };
  const long TD = (long)Tz * Dz, TT = (long)Tz * Tz;

  unsigned short* w_qkvt  = (unsigned short*)alloc((size_t)3072*1024*2);
  unsigned short* w_outt  = (unsigned short*)alloc((size_t)1024*1024*2);
  unsigned short* w_ew1t  = (unsigned short*)alloc((size_t)2048*1024*2);
  unsigned short* w_ew2t  = (unsigned short*)alloc((size_t)1024*2048*2);
  unsigned short* w_qkv2t = (unsigned short*)alloc((size_t)3072*1024*2); // [wq|wk|wv]^T
  unsigned short* w_wot   = (unsigned short*)alloc((size_t)1024*1024*2);
  unsigned short* h1bf    = (unsigned short*)alloc((size_t)NTz*Dz*2);
  unsigned short* qkvb    = (unsigned short*)alloc((size_t)NTz*3072*2);  // 24 MB
  unsigned short* aobf    = (unsigned short*)alloc((size_t)NTz*Dz*2);
  float*          x2f     = (float*)alloc((size_t)NTz*Dz*4);
  unsigned short* hbf     = (unsigned short*)alloc((size_t)NTz*Dz*2);
  unsigned short* Pbf     = (unsigned short*)alloc((size_t)Bz*Tz*Tz*2);
  unsigned short* qkv2b   = (unsigned short*)alloc((size_t)NTz*3072*2);  // 24 MB
  unsigned short* v2tbf   = (unsigned short*)alloc((size_t)NTz*Dz*2);
  unsigned short* a2obf   = (unsigned short*)alloc((size_t)NTz*Dz*2);
  float*          eof_    = (float*)alloc((size_t)NTz*Dz*4);
  float*          a2pf    = (float*)alloc((size_t)NTz*Dz*4);

  // aliases (lifetime-disjoint):
  unsigned short* e1bf = qkvb;                         // dead after qkvsplit; e1 written later
  float*          Sf   = (float*)(qkvb + (size_t)8*1024*1024/2 + 4*1024*1024); // 16MB at +16MB (spills into aobf, dead by then)
  unsigned short* Qb = (unsigned short*)x2f;           // x2f written after attn
  unsigned short* Kb = Pbf;                            // Pbf written after attn
  unsigned short* Vt = (unsigned short*)a2pf;          // a2pf written after attn

  dim3 blk(256);

  // weight convert+transpose -> bf16 (N x K)
  k_convtrans<<<dim3(96, 32), blk, 0, stream>>>(qkv_w, w_qkvt, 1024, 3072);
  k_convtrans<<<dim3(32, 32), blk, 0, stream>>>(out_w, w_outt, 1024, 1024);
  k_convtrans<<<dim3(64, 32), blk, 0, stream>>>(ew1,   w_ew1t, 1024, 2048);
  k_convtrans<<<dim3(32, 64), blk, 0, stream>>>(ew2,   w_ew2t, 2048, 1024);
  k_convtrans<<<dim3(32, 32), blk, 0, stream>>>(at_wq, w_qkv2t,               1024, 1024);
  k_convtrans<<<dim3(32, 32), blk, 0, stream>>>(at_wk, w_qkv2t + 1024*1024,   1024, 1024);
  k_convtrans<<<dim3(32, 32), blk, 0, stream>>>(at_wv, w_qkv2t + 2*1024*1024, 1024, 1024);
  k_convtrans<<<dim3(32, 32), blk, 0, stream>>>(at_wo, w_wot, 1024, 1024);

  // backbone
  k_layernorm<<<NTz, blk, 0, stream>>>(x, ln1_w, ln1_b, h1bf);
  k_gemm<3,128,false,false,false><<<dim3(24, 32), blk, 0, stream>>>(h1bf, w_qkvt, nullptr,
      qkvb, nullptr, 3072, 1024, 1024, 1024, 0, 0, 0);
  k_qkvsplit<<<dim3(32, 64), blk, 0, stream>>>(qkvb, Qb, Kb, Vt);
  k_attn_mfma<<<dim3(1024), blk, 0, stream>>>(Qb, Kb, Vt, aobf);
  k_gemm<1,64,false,false,true><<<dim3(16, 32), blk, 0, stream>>>(aobf, w_outt, x2f,
      nullptr, x, 1024, 1024, 1024, 1024, 0, 0, 0);
  // tiers
  k_layernorm<<<NTz, blk, 0, stream>>>(x2f, ln2_w, ln2_b, hbf);
  k_router<<<NTz, blk, 0, stream>>>(hbf, router_w, rout);
  k_gemm<2,128,false,false,false><<<dim3(16, 32), blk, 0, stream>>>(hbf, w_ew1t, nullptr,
      e1bf, nullptr, 2048, 1024, 1024, 1024, 0, 0, 0);
  k_gemm<0,64,false,false,true><<<dim3(16, 32), blk, 0, stream>>>(e1bf, w_ew2t, eof_,
      nullptr, nullptr, 1024, 2048, 2048, 2048, 0, 0, 0);
  k_gemm<3,128,false,false,false><<<dim3(24, 32), blk, 0, stream>>>(hbf, w_qkv2t, nullptr,
      qkv2b, nullptr, 3072, 1024, 1024, 1024, 0, 0, 0);
  k_convtrans_b<<<dim3(32, 32, 4), blk, 0, stream>>>(qkv2b + 2048, v2tbf, 3072,
      (long)Tz*3072, TD);
  k_gemm<0,64,true,false,true><<<dim3(72, 1, 4), blk, 0, stream>>>(qkv2b, qkv2b + 1024, Sf,
      nullptr, nullptr, 1024, 1024, 3072, 3072, (long)Tz*3072, (long)Tz*3072, TT);
  k_softmax_causal<<<NTz, blk, 0, stream>>>(Sf, Pbf, 0.03125f);
  k_gemm<3,64,false,true,true><<<dim3(16, 8, 4), blk, 0, stream>>>(Pbf, v2tbf, nullptr,
      a2obf, nullptr, 1024, 1024, 1024, 1024, TT, TD, TD);
  k_gemm<0,64,false,false,true><<<dim3(16, 32), blk, 0, stream>>>(a2obf, w_wot, a2pf,
      nullptr, nullptr, 1024, 1024, 1024, 1024, 0, 0, 0);
  k_combine<<<NTz, blk, 0, stream>>>(x2f, hbf, eof_, a2pf, rout, conv_w, tg, sinkp, outx);
}